// Round 4
// baseline (1919.693 us; speedup 1.0000x reference)
//
#include <hip/hip_runtime.h>
#include <hip/hip_bf16.h>

typedef __hip_bfloat16 bf16;

#define NSTEP 6

static __device__ __forceinline__ float b2f(bf16 v) { return __bfloat162float(v); }

// dtype-dispatched param load: md==0 -> bf16, md==1 -> float32
static __device__ __forceinline__ float ldp(const void* p, int i, int md) {
    return md ? ((const float*)p)[i] : b2f(((const bf16*)p)[i]);
}
static __device__ __forceinline__ float finz(float v) {
    return (v == v && v * 0.0f == 0.0f) ? v : 0.0f;  // non-finite -> 0
}

// ---------------- detect / pack / cast kernels ----------------

// flags[0]: masks dtype mode (0 int32, 1 u8, 2 16-bit, 3 f32)
// flags[1]: float-array dtype (0 bf16, 1 f32), from x's byte patterns
// also zeroes accv (96 floats)
__global__ void k_detect(const unsigned char* __restrict__ m,
                         const unsigned char* __restrict__ xb,
                         int* __restrict__ flags, float* __restrict__ accv) {
    __shared__ int s3f, sup, slo, sf32;
    int t = threadIdx.x;
    if (t == 0) { s3f = 0; sup = 0; slo = 0; sf32 = 0; }
    if (t < 96) accv[t] = 0.f;
    __syncthreads();
    int l3f = 0, lup = 0, llo = 0, lf = 0;
    for (int i = t; i < 49152; i += 256) {
        unsigned char v = m[i];
        if (v == 0x3F) l3f = 1;
        if ((i & 3) != 0 && v != 0) lup = 1;
        if ((i & 3) < 2 && v != 0) llo = 1;
    }
    // x: if bf16 (|v|<8), byte at offset 1 mod 4 is a bf16 high byte with
    // (b&0x7F) <= 0x41. If f32, that byte is uniform mantissa -> exceeds 0x48
    // within 16k samples with certainty.
    for (int i = t * 4 + 1; i < 65536; i += 1024) {
        unsigned char v = xb[i];
        if ((v & 0x7F) > 0x48) lf = 1;
    }
    if (l3f) atomicOr(&s3f, 1);
    if (lup) atomicOr(&sup, 1);
    if (llo) atomicOr(&slo, 1);
    if (lf)  atomicOr(&sf32, 1);
    __syncthreads();
    if (t == 0) {
        int mode;
        if (!s3f && !sup) mode = 0;
        else if (!s3f)    mode = 1;
        else if (slo)     mode = 2;
        else              mode = 3;
        flags[0] = mode;
        flags[1] = sf32;
    }
}

__global__ void k_cast(const void* __restrict__ in, float* __restrict__ out,
                       const int* __restrict__ mflags, int n) {
    int md = mflags[1];
    int i = blockIdx.x * 256 + threadIdx.x;
    if (i < n) out[i] = finz(ldp(in, i, md));
}

// out[k*R + r] = in[r*K + k]
__global__ void k_transpose(const void* __restrict__ in, float* __restrict__ out,
                            const int* __restrict__ mflags, int R, int K) {
    int md = mflags[1];
    int i = blockIdx.x * 256 + threadIdx.x;
    if (i < R * K) {
        int k = i / R, r = i % R;
        out[i] = ldp(in, r * K + k, md);
    }
}

// wpk[(i*9+k)*128 + o] : o<64 -> p0_w[o][i][k], else p1_w[o-64][i][k]
__global__ void k_pack_conv(const void* __restrict__ p0, const void* __restrict__ p1,
                            float* __restrict__ out, const int* __restrict__ mflags) {
    int md = mflags[1];
    int i = blockIdx.x * 256 + threadIdx.x;
    if (i < 64 * 9 * 128) {
        int o = i & 127, kidx = i >> 7;
        out[i] = (o < 64) ? ldp(p0, o * 576 + kidx, md) : ldp(p1, (o - 64) * 576 + kidx, md);
    }
}

// ---------------- step kernels ----------------
// grid 512 = B*H rows, 256 threads everywhere.

// A: perception (2 reflect-pad 3x3 convs) + fc0 + relu -> hd (bf16); partial LN sums
__global__ __launch_bounds__(256) void k_perceive(
    const float* __restrict__ xin, const float* __restrict__ wpk,
    const float* __restrict__ fc0t, const void* __restrict__ p0b,
    const void* __restrict__ p1b, const void* __restrict__ fc0b,
    const int* __restrict__ mflags, bf16* __restrict__ hd,
    float* __restrict__ accv, int step)
{
    __shared__ float sm[12864];   // phase1: x [ch=64][row=3][wp=67] stride 201/67; phase2: p [pos][193]
    int md = mflags[1];
    int bh = blockIdx.x;
    int b = bh >> 6, h = bh & 63;
    int t = threadIdx.x;

    // stage 3 rows of x with reflect padding, transposed layout
    // padded row P[0..65]: P[j]=x[j-1] for j=1..64, P[0]=x[1], P[65]=x[62]
    for (int e = t; e < 3 * 64 * 64; e += 256) {
        int c = e & 63, w = (e >> 6) & 63, r = e >> 12;
        int hr = h - 1 + r; hr = hr < 0 ? -hr : (hr > 63 ? 126 - hr : hr);
        float v = xin[(((b << 6) + hr) << 6 | w) * 64 + c];
        int base = c * 201 + r * 67;
        sm[base + w + 1] = v;
        if (w == 1)  sm[base]      = v;   // reflect left  (P[0]  = x[1])
        if (w == 62) sm[base + 65] = v;   // reflect right (P[65] = x[62])
    }
    __syncthreads();

    int og  = __builtin_amdgcn_readfirstlane(t >> 6);  // wave-uniform group 0..3
    int pos = t & 63;

    // conv: this thread computes 32 of the 128 conv outputs (y1:0..63, y2:64..127)
    float acc[32];
#pragma unroll
    for (int oi = 0; oi < 32; ++oi) {
        int oa = og * 32 + oi;
        acc[oi] = (oa < 64) ? ldp(p0b, oa, md) : ldp(p1b, oa - 64, md);
    }
    for (int i = 0; i < 64; ++i) {
        float xv[9];
#pragma unroll
        for (int r = 0; r < 3; ++r)
#pragma unroll
            for (int cxi = 0; cxi < 3; ++cxi)
                xv[r * 3 + cxi] = sm[i * 201 + r * 67 + pos + cxi];
        const float* wp = wpk + (i * 9) * 128 + og * 32;
#pragma unroll
        for (int k = 0; k < 9; ++k) {
#pragma unroll
            for (int oi = 0; oi < 32; ++oi)
                acc[oi] = fmaf(wp[k * 128 + oi], xv[k], acc[oi]);
        }
    }
    // keep my 16 channels of the raw x (center pixel) for the concat
    float xreg[16];
#pragma unroll
    for (int j = 0; j < 16; ++j)
        xreg[j] = sm[(og * 16 + j) * 201 + 67 + pos + 1];
    __syncthreads();

    // build p = [x(64), y1(64), y2(64)] in LDS, [pos][193]
#pragma unroll
    for (int j = 0; j < 16; ++j) sm[pos * 193 + og * 16 + j] = xreg[j];
#pragma unroll
    for (int oi = 0; oi < 32; ++oi) sm[pos * 193 + 64 + og * 32 + oi] = acc[oi];
    __syncthreads();

    // fc0: 32 of 128 hidden outputs per thread, relu, store; LN partials
#pragma unroll
    for (int jj = 0; jj < 32; ++jj) acc[jj] = ldp(fc0b, og * 32 + jj, md);
    for (int kk = 0; kk < 192; ++kk) {
        float pv = sm[pos * 193 + kk];
        const float* fw = fc0t + kk * 128 + og * 32;
#pragma unroll
        for (int jj = 0; jj < 32; ++jj)
            acc[jj] = fmaf(fw[jj], pv, acc[jj]);
    }
    float lsum = 0.f, lsq = 0.f;
    bf16* hrow = hd + ((((b << 6) + h) << 6) + pos) * 128;
#pragma unroll
    for (int jj = 0; jj < 32; ++jj) {
        bf16 hv = __float2bfloat16(fmaxf(acc[jj], 0.f));
        hrow[og * 32 + jj] = hv;
        float vr = b2f(hv);          // stats from the rounded value we store
        lsum += vr; lsq += vr * vr;
    }
    __syncthreads();
    sm[t] = lsum; sm[256 + t] = lsq;
    __syncthreads();
    for (int s2 = 128; s2 > 0; s2 >>= 1) {
        if (t < s2) { sm[t] += sm[t + s2]; sm[256 + t] += sm[256 + t + s2]; }
        __syncthreads();
    }
    if (t == 0) {
        atomicAdd(&accv[step * 16 + b * 2],     sm[0]);
        atomicAdd(&accv[step * 16 + b * 2 + 1], sm[256]);
    }
}

// B: global layernorm over [H,W,HID] + fc1 + mask + residual, IN-PLACE on x.
// Stashes pre-update channel 0 into c0buf for the end-of-step restore.
__global__ __launch_bounds__(256) void k_update(
    float* __restrict__ xio, const bf16* __restrict__ hd,
    const float* __restrict__ fc1t, const void* __restrict__ n0w,
    const void* __restrict__ n0b, const void* __restrict__ mraw,
    const int* __restrict__ mflags, const float* __restrict__ accv,
    float* __restrict__ c0buf, int step)
{
    __shared__ float hdn[64 * 129];
    int md = mflags[1];
    int bh = blockIdx.x;
    int b = bh >> 6, h = bh & 63;
    int t = threadIdx.x;
    const float invN = 1.f / 524288.f;
    float mean = accv[step * 16 + b * 2] * invN;
    float var  = accv[step * 16 + b * 2 + 1] * invN - mean * mean;
    float rstd = rsqrtf(fmaxf(var, 0.f) + 1e-5f);

    const bf16* hrow = hd + ((b * 64 + h) * 64) * 128;
    for (int e = t; e < 8192; e += 256) {
        int pos = e >> 7, j = e & 127;
        float v  = b2f(hrow[e]);
        int ni   = (h * 64 + pos) * 128 + j;
        hdn[pos * 129 + j] = (v - mean) * rstd * ldp(n0w, ni, md) + ldp(n0b, ni, md);
    }
    __syncthreads();

    int cg  = __builtin_amdgcn_readfirstlane(t >> 6);
    int pos = t & 63;
    float acc[16];
#pragma unroll
    for (int ci = 0; ci < 16; ++ci) acc[ci] = 0.f;
    for (int j = 0; j < 128; ++j) {
        float hv = hdn[pos * 129 + j];
        const float* fw = fc1t + j * 64 + cg * 16;
#pragma unroll
        for (int ci = 0; ci < 16; ++ci) acc[ci] = fmaf(fw[ci], hv, acc[ci]);
    }
    int mmode = mflags[0];
    int midx = ((step * 8 + b) * 64 + h) * 64 + pos;
    int m;
    if (mmode == 0)      m = ((const int*)mraw)[midx] != 0;
    else if (mmode == 1) m = ((const unsigned char*)mraw)[midx] != 0;
    else if (mmode == 2) m = ((const unsigned short*)mraw)[midx] != 0;
    else                 m = ((const float*)mraw)[midx] != 0.0f;

    int idx = ((b * 64 + h) * 64 + pos) * 64 + cg * 16;
#pragma unroll
    for (int ci = 0; ci < 16; ++ci) {
        float xv = xio[idx + ci];
        if (cg == 0 && ci == 0) c0buf[(b * 64 + h) * 64 + pos] = xv;  // pre-update ch0
        xio[idx + ci] = finz(m ? (xv + acc[ci]) : xv);
    }
}

// C1: per-token LN (ln1) + qkv projection -> qkv bf16 [B,4096,192]
__global__ __launch_bounds__(256) void k_qkv(
    const float* __restrict__ xn, const float* __restrict__ qkvt,
    const void* __restrict__ ln1w, const void* __restrict__ ln1b,
    const int* __restrict__ mflags, bf16* __restrict__ qkv)
{
    __shared__ float ys[64 * 65];
    int md = mflags[1];
    int bh = blockIdx.x;
    int b = bh >> 6, h = bh & 63;
    int t = threadIdx.x;
    const float* xrow = xn + ((b * 64 + h) * 64) * 64;
    for (int e = t; e < 4096; e += 256) ys[(e >> 6) * 65 + (e & 63)] = xrow[e];
    __syncthreads();
    if (t < 64) {
        float s = 0.f, sq = 0.f;
        for (int c = 0; c < 64; ++c) { float v = ys[t * 65 + c]; s += v; sq += v * v; }
        float mu = s * (1.f / 64.f);
        float var = sq * (1.f / 64.f) - mu * mu;
        float rs = rsqrtf(fmaxf(var, 0.f) + 1e-5f);
        for (int c = 0; c < 64; ++c) {
            float v = ys[t * 65 + c];
            ys[t * 65 + c] = (v - mu) * rs * ldp(ln1w, c, md) + ldp(ln1b, c, md);
        }
    }
    __syncthreads();
    int g   = __builtin_amdgcn_readfirstlane(t >> 6);
    int pos = t & 63;
    float acc[48];
#pragma unroll
    for (int oi = 0; oi < 48; ++oi) acc[oi] = 0.f;
    for (int c = 0; c < 64; ++c) {
        float yv = ys[pos * 65 + c];
        const float* qw = qkvt + c * 192 + g * 48;
#pragma unroll
        for (int oi = 0; oi < 48; ++oi) acc[oi] = fmaf(qw[oi], yv, acc[oi]);
    }
    bf16* qrow = qkv + (((b * 64 + h) * 64) + pos) * 192 + g * 48;
#pragma unroll
    for (int oi = 0; oi < 48; ++oi) qrow[oi] = __float2bfloat16(acc[oi]);
}

// C2+D fused: 3x3 zero-padded local attention + out-proj + residual (t),
// then ln2 + GELU MLP + residual + ch0 restore; writes state in-place and
// (last step) d_out in the detected dtype.
__global__ __launch_bounds__(256) void k_attn_ff(
    const bf16* __restrict__ qkv, float* __restrict__ xio,
    const float* __restrict__ c0buf, const float* __restrict__ outt,
    const float* __restrict__ ff1t, const float* __restrict__ ff2t,
    const void* __restrict__ outb, const void* __restrict__ ln2w,
    const void* __restrict__ ln2b, const void* __restrict__ ff1b,
    const void* __restrict__ ff2b, const int* __restrict__ mflags,
    void* __restrict__ dout, int write_out)
{
    // region map (floats): [0,12736) KV tiles (stride 199/66), then
    // os=[0,4160) o-frags / later hs; ts=[4224,8384); ys=[8448,12608)
    __shared__ float sm[12736];
    int md = mflags[1];
    int bh = blockIdx.x;
    int b = bh >> 6, h = bh & 63;
    int t = threadIdx.x;

    // zero the left/right halo slots (stay zero through K and V phases)
    if (t < 192) {
        int c = t & 63, r = t >> 6;
        sm[c * 199 + r * 66]      = 0.f;
        sm[c * 199 + r * 66 + 65] = 0.f;
    }
    // load K (qkv channels 64..127), zero rows out of range
    for (int e = t; e < 3 * 64 * 64; e += 256) {
        int c = e & 63, w = (e >> 6) & 63, r = e >> 12;
        int hr = h - 1 + r;
        float v = (hr >= 0 && hr <= 63) ? b2f(qkv[((b * 64 + hr) * 64 + w) * 192 + 64 + c]) : 0.f;
        sm[c * 199 + r * 66 + w + 1] = v;
    }
    __syncthreads();

    int head = __builtin_amdgcn_readfirstlane(t >> 6);
    int pos  = t & 63;
    float q[16];
    const bf16* qrow = qkv + (((b * 64 + h) * 64) + pos) * 192 + head * 16;
#pragma unroll
    for (int d = 0; d < 16; ++d) q[d] = b2f(qrow[d]);

    float a[9];
#pragma unroll
    for (int r = 0; r < 3; ++r)
#pragma unroll
        for (int cxi = 0; cxi < 3; ++cxi) {
            float dot = 0.f;
#pragma unroll
            for (int d = 0; d < 16; ++d)
                dot = fmaf(q[d], sm[(head * 16 + d) * 199 + r * 66 + pos + cxi], dot);
            a[r * 3 + cxi] = dot * 0.25f;   // SCALE = 16^-0.5
        }
    float mx = a[0];
#pragma unroll
    for (int k = 1; k < 9; ++k) mx = fmaxf(mx, a[k]);
    float ssum = 0.f;
#pragma unroll
    for (int k = 0; k < 9; ++k) { a[k] = __expf(a[k] - mx); ssum += a[k]; }
    float inv = 1.f / ssum;
#pragma unroll
    for (int k = 0; k < 9; ++k) a[k] *= inv;
    __syncthreads();

    // reload interior with V (qkv channels 128..191); halo still zero
    for (int e = t; e < 3 * 64 * 64; e += 256) {
        int c = e & 63, w = (e >> 6) & 63, r = e >> 12;
        int hr = h - 1 + r;
        float v = (hr >= 0 && hr <= 63) ? b2f(qkv[((b * 64 + hr) * 64 + w) * 192 + 128 + c]) : 0.f;
        sm[c * 199 + r * 66 + w + 1] = v;
    }
    __syncthreads();

    float o[16];
#pragma unroll
    for (int d = 0; d < 16; ++d) {
        float ov = 0.f;
#pragma unroll
        for (int r = 0; r < 3; ++r)
#pragma unroll
            for (int cxi = 0; cxi < 3; ++cxi)
                ov = fmaf(a[r * 3 + cxi], sm[(head * 16 + d) * 199 + r * 66 + pos + cxi], ov);
        o[d] = ov;
    }
    __syncthreads();
    // os[pos][64]
#pragma unroll
    for (int d = 0; d < 16; ++d) sm[pos * 65 + head * 16 + d] = o[d];
    __syncthreads();

    int g = head;
    float acc[16];
#pragma unroll
    for (int ci = 0; ci < 16; ++ci) acc[ci] = ldp(outb, g * 16 + ci, md);
    for (int k = 0; k < 64; ++k) {
        float ov = sm[pos * 65 + k];
        const float* ow = outt + k * 64 + g * 16;
#pragma unroll
        for (int ci = 0; ci < 16; ++ci) acc[ci] = fmaf(ow[ci], ov, acc[ci]);
    }
    int idx = ((b * 64 + h) * 64 + pos) * 64 + g * 16;
    // t = xn + attn_out -> ts region
#pragma unroll
    for (int ci = 0; ci < 16; ++ci)
        sm[4224 + pos * 65 + g * 16 + ci] = xio[idx + ci] + acc[ci];
    __syncthreads();

    // ln2 per token -> ys region
    if (t < 64) {
        float s = 0.f, sq = 0.f;
        for (int c = 0; c < 64; ++c) { float v = sm[4224 + t * 65 + c]; s += v; sq += v * v; }
        float mu = s * (1.f / 64.f);
        float var = sq * (1.f / 64.f) - mu * mu;
        float rs = rsqrtf(fmaxf(var, 0.f) + 1e-5f);
        for (int c = 0; c < 64; ++c) {
            float v = sm[4224 + t * 65 + c];
            sm[8448 + t * 65 + c] = (v - mu) * rs * ldp(ln2w, c, md) + ldp(ln2b, c, md);
        }
    }
    __syncthreads();

    // MLP1 + exact GELU -> hs (os region, dead)
#pragma unroll
    for (int mi = 0; mi < 16; ++mi) acc[mi] = ldp(ff1b, g * 16 + mi, md);
    for (int c = 0; c < 64; ++c) {
        float yv = sm[8448 + pos * 65 + c];
        const float* fw = ff1t + c * 64 + g * 16;
#pragma unroll
        for (int mi = 0; mi < 16; ++mi) acc[mi] = fmaf(fw[mi], yv, acc[mi]);
    }
    __syncthreads();
#pragma unroll
    for (int mi = 0; mi < 16; ++mi) {
        float v = acc[mi];
        sm[pos * 65 + g * 16 + mi] = 0.5f * v * (1.f + erff(v * 0.70710678118654752f));
    }
    __syncthreads();

    // MLP2 + residual + ch0 restore + state/out write
#pragma unroll
    for (int ci = 0; ci < 16; ++ci) acc[ci] = ldp(ff2b, g * 16 + ci, md);
    for (int m = 0; m < 64; ++m) {
        float hv = sm[pos * 65 + m];
        const float* fw = ff2t + m * 64 + g * 16;
#pragma unroll
        for (int ci = 0; ci < 16; ++ci) acc[ci] = fmaf(fw[ci], hv, acc[ci]);
    }
#pragma unroll
    for (int ci = 0; ci < 16; ++ci) {
        float fv = sm[4224 + pos * 65 + g * 16 + ci] + acc[ci];
        if (g == 0 && ci == 0) fv = c0buf[(b * 64 + h) * 64 + pos];  // keep input ch0
        fv = finz(fv);
        xio[idx + ci] = fv;
        if (write_out) {
            if (md) ((float*)dout)[idx + ci] = fv;
            else    ((bf16*)dout)[idx + ci] = __float2bfloat16(fv);
        }
    }
}

// ---------------- launch ----------------

extern "C" void kernel_launch(void* const* d_in, const int* in_sizes, int n_in,
                              void* d_out, int out_size, void* d_ws, size_t ws_size,
                              hipStream_t stream) {
    (void)in_sizes; (void)n_in; (void)out_size; (void)ws_size;
    const void* x     = d_in[0];
    const void* masks = d_in[1];
    const void* p0w   = d_in[2];
    const void* p0b   = d_in[3];
    const void* p1w   = d_in[4];
    const void* p1b   = d_in[5];
    const void* fc0w  = d_in[6];
    const void* fc0b  = d_in[7];
    const void* fc1w  = d_in[8];
    const void* n0w   = d_in[9];
    const void* n0b   = d_in[10];
    const void* ln1w  = d_in[11];
    const void* ln1b  = d_in[12];
    const void* qkvw  = d_in[13];
    const void* outw  = d_in[14];
    const void* outb  = d_in[15];
    const void* ln2w  = d_in[16];
    const void* ln2b  = d_in[17];
    const void* ff1w  = d_in[18];
    const void* ff1b  = d_in[19];
    const void* ff2w  = d_in[20];
    const void* ff2b  = d_in[21];

    // compact workspace layout, ~21.6 MB total.
    // hd (bf16, perceive->update) and qkvb (bf16, qkv->attn_ff) share one
    // region: non-overlapping lifetimes within a step.
    char* wsb = (char*)d_ws;
    float* xst    = (float*)(wsb + 0);           //  8,388,608 B  fp32 state (in-place)
    bf16*  hd     = (bf16*) (wsb + 8388608);     // 12,582,912 B region
    bf16*  qkvb   = (bf16*) (wsb + 8388608);     //   (alias of hd)
    float* c0buf  = (float*)(wsb + 20971520);    //    131,072 B
    float* wpk    = (float*)(wsb + 21102592);    //    294,912 B
    float* fc0t   = (float*)(wsb + 21397504);    //     98,304 B
    float* fc1t   = (float*)(wsb + 21495808);    //     32,768 B
    float* qkvt   = (float*)(wsb + 21528576);    //     49,152 B
    float* outt   = (float*)(wsb + 21577728);    //     16,384 B
    float* ff1t   = (float*)(wsb + 21594112);    //     16,384 B
    float* ff2t   = (float*)(wsb + 21610496);    //     16,384 B
    float* accv   = (float*)(wsb + 21626880);    //        384 B
    int*   mflags = (int*)  (wsb + 21627264);    //         16 B

    k_detect<<<1, 256, 0, stream>>>((const unsigned char*)masks,
                                    (const unsigned char*)x, mflags, accv);
    k_cast<<<8192, 256, 0, stream>>>(x, xst, mflags, 2097152);
    k_pack_conv<<<288, 256, 0, stream>>>(p0w, p1w, wpk, mflags);
    k_transpose<<<96, 256, 0, stream>>>(fc0w, fc0t, mflags, 128, 192);
    k_transpose<<<32, 256, 0, stream>>>(fc1w, fc1t, mflags, 64, 128);
    k_transpose<<<48, 256, 0, stream>>>(qkvw, qkvt, mflags, 192, 64);
    k_transpose<<<16, 256, 0, stream>>>(outw, outt, mflags, 64, 64);
    k_transpose<<<16, 256, 0, stream>>>(ff1w, ff1t, mflags, 64, 64);
    k_transpose<<<16, 256, 0, stream>>>(ff2w, ff2t, mflags, 64, 64);

    for (int s = 0; s < NSTEP; ++s) {
        k_perceive<<<512, 256, 0, stream>>>(xst, wpk, fc0t, p0b, p1b, fc0b, mflags, hd, accv, s);
        k_update<<<512, 256, 0, stream>>>(xst, hd, fc1t, n0w, n0b, masks, mflags, accv, c0buf, s);
        k_qkv<<<512, 256, 0, stream>>>(xst, qkvt, ln1w, ln1b, mflags, qkvb);
        k_attn_ff<<<512, 256, 0, stream>>>(qkvb, xst, c0buf, outt, ff1t, ff2t,
                                           outb, ln2w, ln2b, ff1b, ff2b, mflags,
                                           d_out, (s == NSTEP - 1) ? 1 : 0);
    }
}

// Round 5
// 1657.486 us; speedup vs baseline: 1.1582x; 1.1582x over previous
//
#include <hip/hip_runtime.h>
#include <hip/hip_bf16.h>

typedef __hip_bfloat16 bf16;

#define NSTEP 6

static __device__ __forceinline__ float b2f(bf16 v) { return __bfloat162float(v); }

// dtype-dispatched param load: md==0 -> bf16, md==1 -> float32
static __device__ __forceinline__ float ldp(const void* p, int i, int md) {
    return md ? ((const float*)p)[i] : b2f(((const bf16*)p)[i]);
}
static __device__ __forceinline__ float finz(float v) {
    return (v == v && v * 0.0f == 0.0f) ? v : 0.0f;  // non-finite -> 0
}

// ---------------- detect / pack / cast kernels ----------------

// flags[0]: masks dtype mode (0 int32, 1 u8, 2 16-bit, 3 f32)
// flags[1]: float-array dtype (0 bf16, 1 f32), from x's byte patterns
// also zeroes accv (96 floats)
__global__ void k_detect(const unsigned char* __restrict__ m,
                         const unsigned char* __restrict__ xb,
                         int* __restrict__ flags, float* __restrict__ accv) {
    __shared__ int s3f, sup, slo, sf32;
    int t = threadIdx.x;
    if (t == 0) { s3f = 0; sup = 0; slo = 0; sf32 = 0; }
    if (t < 96) accv[t] = 0.f;
    __syncthreads();
    int l3f = 0, lup = 0, llo = 0, lf = 0;
    for (int i = t; i < 49152; i += 256) {
        unsigned char v = m[i];
        if (v == 0x3F) l3f = 1;
        if ((i & 3) != 0 && v != 0) lup = 1;
        if ((i & 3) < 2 && v != 0) llo = 1;
    }
    for (int i = t * 4 + 1; i < 65536; i += 1024) {
        unsigned char v = xb[i];
        if ((v & 0x7F) > 0x48) lf = 1;
    }
    if (l3f) atomicOr(&s3f, 1);
    if (lup) atomicOr(&sup, 1);
    if (llo) atomicOr(&slo, 1);
    if (lf)  atomicOr(&sf32, 1);
    __syncthreads();
    if (t == 0) {
        int mode;
        if (!s3f && !sup) mode = 0;
        else if (!s3f)    mode = 1;
        else if (slo)     mode = 2;
        else              mode = 3;
        flags[0] = mode;
        flags[1] = sf32;
    }
}

__global__ void k_cast(const void* __restrict__ in, float* __restrict__ out,
                       const int* __restrict__ mflags, int n) {
    int md = mflags[1];
    int i = blockIdx.x * 256 + threadIdx.x;
    if (i < n) out[i] = finz(ldp(in, i, md));
}

// out[k*R + r] = in[r*K + k]
__global__ void k_transpose(const void* __restrict__ in, float* __restrict__ out,
                            const int* __restrict__ mflags, int R, int K) {
    int md = mflags[1];
    int i = blockIdx.x * 256 + threadIdx.x;
    if (i < R * K) {
        int k = i / R, r = i % R;
        out[i] = ldp(in, r * K + k, md);
    }
}

// wpk[(i*9+k)*128 + o] : o<64 -> p0_w[o][i][k], else p1_w[o-64][i][k]
__global__ void k_pack_conv(const void* __restrict__ p0, const void* __restrict__ p1,
                            float* __restrict__ out, const int* __restrict__ mflags) {
    int md = mflags[1];
    int i = blockIdx.x * 256 + threadIdx.x;
    if (i < 64 * 9 * 128) {
        int o = i & 127, kidx = i >> 7;
        out[i] = (o < 64) ? ldp(p0, o * 576 + kidx, md) : ldp(p1, (o - 64) * 576 + kidx, md);
    }
}

// ---------------- step kernels ----------------
// grid 512 = B*H rows, 512 threads (8 waves) per block -> 16 waves/CU.

// A: perception (2 reflect-pad 3x3 convs) + fc0 + relu -> hd (bf16); partial LN sums
__global__ __launch_bounds__(512) void k_perceive(
    const float* __restrict__ xin, const float* __restrict__ wpk,
    const float* __restrict__ fc0t, const void* __restrict__ p0b,
    const void* __restrict__ p1b, const void* __restrict__ fc0b,
    const int* __restrict__ mflags, bf16* __restrict__ hd,
    float* __restrict__ accv, int step)
{
    __shared__ float sm[12864];   // phase1: x [ch=64][row=3][wp=67] stride 201/67; phase2: p [pos][193]
    int md = mflags[1];
    int bh = blockIdx.x;
    int b = bh >> 6, h = bh & 63;
    int t = threadIdx.x;

    // stage 3 rows of x with reflect padding, transposed layout
    // padded row P[0..65]: P[j]=x[j-1] for j=1..64, P[0]=x[1], P[65]=x[62]
    for (int e = t; e < 3 * 64 * 64; e += 512) {
        int c = e & 63, w = (e >> 6) & 63, r = e >> 12;
        int hr = h - 1 + r; hr = hr < 0 ? -hr : (hr > 63 ? 126 - hr : hr);
        float v = xin[(((b << 6) + hr) << 6 | w) * 64 + c];
        int base = c * 201 + r * 67;
        sm[base + w + 1] = v;
        if (w == 1)  sm[base]      = v;   // reflect left  (P[0]  = x[1])
        if (w == 62) sm[base + 65] = v;   // reflect right (P[65] = x[62])
    }
    __syncthreads();

    int og  = __builtin_amdgcn_readfirstlane(t >> 6);  // wave-uniform group 0..7
    int pos = t & 63;

    // conv: this thread computes 16 of the 128 conv outputs (y1:0..63, y2:64..127)
    float acc[16];
#pragma unroll
    for (int oi = 0; oi < 16; ++oi) {
        int oa = og * 16 + oi;
        acc[oi] = (oa < 64) ? ldp(p0b, oa, md) : ldp(p1b, oa - 64, md);
    }
    for (int i = 0; i < 64; ++i) {
        float xv[9];
#pragma unroll
        for (int r = 0; r < 3; ++r)
#pragma unroll
            for (int cxi = 0; cxi < 3; ++cxi)
                xv[r * 3 + cxi] = sm[i * 201 + r * 67 + pos + cxi];
        const float* wp = wpk + (i * 9) * 128 + og * 16;
#pragma unroll
        for (int k = 0; k < 9; ++k) {
#pragma unroll
            for (int oi = 0; oi < 16; ++oi)
                acc[oi] = fmaf(wp[k * 128 + oi], xv[k], acc[oi]);
        }
    }
    // keep my 8 channels of the raw x (center pixel) for the concat
    float xreg[8];
#pragma unroll
    for (int j = 0; j < 8; ++j)
        xreg[j] = sm[(og * 8 + j) * 201 + 67 + pos + 1];
    __syncthreads();

    // build p = [x(64), y1(64), y2(64)] in LDS, [pos][193]
#pragma unroll
    for (int j = 0; j < 8; ++j) sm[pos * 193 + og * 8 + j] = xreg[j];
#pragma unroll
    for (int oi = 0; oi < 16; ++oi) sm[pos * 193 + 64 + og * 16 + oi] = acc[oi];
    __syncthreads();

    // fc0: 16 of 128 hidden outputs per thread, relu, store; LN partials
#pragma unroll
    for (int jj = 0; jj < 16; ++jj) acc[jj] = ldp(fc0b, og * 16 + jj, md);
    for (int kk = 0; kk < 192; ++kk) {
        float pv = sm[pos * 193 + kk];
        const float* fw = fc0t + kk * 128 + og * 16;
#pragma unroll
        for (int jj = 0; jj < 16; ++jj)
            acc[jj] = fmaf(fw[jj], pv, acc[jj]);
    }
    float lsum = 0.f, lsq = 0.f;
    bf16* hrow = hd + ((((b << 6) + h) << 6) + pos) * 128;
#pragma unroll
    for (int jj = 0; jj < 16; ++jj) {
        bf16 hv = __float2bfloat16(fmaxf(acc[jj], 0.f));
        hrow[og * 16 + jj] = hv;
        float vr = b2f(hv);          // stats from the rounded value we store
        lsum += vr; lsq += vr * vr;
    }
    // wave-level shuffle reduction, then cross-wave via LDS
#pragma unroll
    for (int off = 32; off > 0; off >>= 1) {
        lsum += __shfl_down(lsum, off, 64);
        lsq  += __shfl_down(lsq,  off, 64);
    }
    __syncthreads();                   // p-region reads done; reuse sm[0..31]
    if ((t & 63) == 0) { sm[og] = lsum; sm[16 + og] = lsq; }
    __syncthreads();
    if (t == 0) {
        float a = 0.f, q = 0.f;
#pragma unroll
        for (int w = 0; w < 8; ++w) { a += sm[w]; q += sm[16 + w]; }
        atomicAdd(&accv[step * 16 + b * 2],     a);
        atomicAdd(&accv[step * 16 + b * 2 + 1], q);
    }
}

// B: global layernorm over [H,W,HID] + fc1 + mask + residual, IN-PLACE on x.
// Stashes pre-update channel 0 into c0buf for the end-of-step restore.
__global__ __launch_bounds__(512) void k_update(
    float* __restrict__ xio, const bf16* __restrict__ hd,
    const float* __restrict__ fc1t, const void* __restrict__ n0w,
    const void* __restrict__ n0b, const void* __restrict__ mraw,
    const int* __restrict__ mflags, const float* __restrict__ accv,
    float* __restrict__ c0buf, int step)
{
    __shared__ float hdn[64 * 129];
    int md = mflags[1];
    int bh = blockIdx.x;
    int b = bh >> 6, h = bh & 63;
    int t = threadIdx.x;
    const float invN = 1.f / 524288.f;
    float mean = accv[step * 16 + b * 2] * invN;
    float var  = accv[step * 16 + b * 2 + 1] * invN - mean * mean;
    float rstd = rsqrtf(fmaxf(var, 0.f) + 1e-5f);

    const bf16* hrow = hd + ((b * 64 + h) * 64) * 128;
    for (int e = t; e < 8192; e += 512) {
        int pos = e >> 7, j = e & 127;
        float v  = b2f(hrow[e]);
        int ni   = (h * 64 + pos) * 128 + j;
        hdn[pos * 129 + j] = (v - mean) * rstd * ldp(n0w, ni, md) + ldp(n0b, ni, md);
    }
    __syncthreads();

    int cg  = __builtin_amdgcn_readfirstlane(t >> 6);   // 0..7
    int pos = t & 63;
    float acc[8];
#pragma unroll
    for (int ci = 0; ci < 8; ++ci) acc[ci] = 0.f;
    for (int j = 0; j < 128; ++j) {
        float hv = hdn[pos * 129 + j];
        const float* fw = fc1t + j * 64 + cg * 8;
#pragma unroll
        for (int ci = 0; ci < 8; ++ci) acc[ci] = fmaf(fw[ci], hv, acc[ci]);
    }
    int mmode = mflags[0];
    int midx = ((step * 8 + b) * 64 + h) * 64 + pos;
    int m;
    if (mmode == 0)      m = ((const int*)mraw)[midx] != 0;
    else if (mmode == 1) m = ((const unsigned char*)mraw)[midx] != 0;
    else if (mmode == 2) m = ((const unsigned short*)mraw)[midx] != 0;
    else                 m = ((const float*)mraw)[midx] != 0.0f;

    int idx = ((b * 64 + h) * 64 + pos) * 64 + cg * 8;
#pragma unroll
    for (int ci = 0; ci < 8; ++ci) {
        float xv = xio[idx + ci];
        if (cg == 0 && ci == 0) c0buf[(b * 64 + h) * 64 + pos] = xv;  // pre-update ch0
        xio[idx + ci] = finz(m ? (xv + acc[ci]) : xv);
    }
}

// C1: per-token LN (ln1) + qkv projection -> qkv bf16 [B,4096,192]
__global__ __launch_bounds__(512) void k_qkv(
    const float* __restrict__ xn, const float* __restrict__ qkvt,
    const void* __restrict__ ln1w, const void* __restrict__ ln1b,
    const int* __restrict__ mflags, bf16* __restrict__ qkv)
{
    __shared__ float ys[64 * 65];
    int md = mflags[1];
    int bh = blockIdx.x;
    int b = bh >> 6, h = bh & 63;
    int t = threadIdx.x;
    const float* xrow = xn + ((b * 64 + h) * 64) * 64;
    for (int e = t; e < 4096; e += 512) ys[(e >> 6) * 65 + (e & 63)] = xrow[e];
    __syncthreads();
    if (t < 64) {
        float s = 0.f, sq = 0.f;
        for (int c = 0; c < 64; ++c) { float v = ys[t * 65 + c]; s += v; sq += v * v; }
        float mu = s * (1.f / 64.f);
        float var = sq * (1.f / 64.f) - mu * mu;
        float rs = rsqrtf(fmaxf(var, 0.f) + 1e-5f);
        for (int c = 0; c < 64; ++c) {
            float v = ys[t * 65 + c];
            ys[t * 65 + c] = (v - mu) * rs * ldp(ln1w, c, md) + ldp(ln1b, c, md);
        }
    }
    __syncthreads();
    int g   = __builtin_amdgcn_readfirstlane(t >> 6);   // 0..7
    int pos = t & 63;
    float acc[24];
#pragma unroll
    for (int oi = 0; oi < 24; ++oi) acc[oi] = 0.f;
    for (int c = 0; c < 64; ++c) {
        float yv = ys[pos * 65 + c];
        const float* qw = qkvt + c * 192 + g * 24;
#pragma unroll
        for (int oi = 0; oi < 24; ++oi) acc[oi] = fmaf(qw[oi], yv, acc[oi]);
    }
    bf16* qrow = qkv + (((b * 64 + h) * 64) + pos) * 192 + g * 24;
#pragma unroll
    for (int oi = 0; oi < 24; ++oi) qrow[oi] = __float2bfloat16(acc[oi]);
}

// C2+D fused: 3x3 zero-padded local attention + out-proj + residual (t),
// then ln2 + GELU MLP + residual + ch0 restore; writes state in-place and
// (last step) d_out in the detected dtype.
// 512 threads: attention math (per head,pos) is duplicated across the two
// half-blocks (cheap, ~300 FMA); staging and all projection/MLP phases use
// the full 512 threads at 8 channels/thread.
__global__ __launch_bounds__(512) void k_attn_ff(
    const bf16* __restrict__ qkv, float* __restrict__ xio,
    const float* __restrict__ c0buf, const float* __restrict__ outt,
    const float* __restrict__ ff1t, const float* __restrict__ ff2t,
    const void* __restrict__ outb, const void* __restrict__ ln2w,
    const void* __restrict__ ln2b, const void* __restrict__ ff1b,
    const void* __restrict__ ff2b, const int* __restrict__ mflags,
    void* __restrict__ dout, int write_out)
{
    // region map (floats): [0,12736) KV tiles (stride 199/66), then
    // os=[0,4160) o-frags / later hs; ts=[4224,8384); ys=[8448,12608)
    __shared__ float sm[12736];
    int md = mflags[1];
    int bh = blockIdx.x;
    int b = bh >> 6, h = bh & 63;
    int t = threadIdx.x;

    // zero the left/right halo slots (stay zero through K and V phases)
    if (t < 192) {
        int c = t & 63, r = t >> 6;
        sm[c * 199 + r * 66]      = 0.f;
        sm[c * 199 + r * 66 + 65] = 0.f;
    }
    // load K (qkv channels 64..127), zero rows out of range
    for (int e = t; e < 3 * 64 * 64; e += 512) {
        int c = e & 63, w = (e >> 6) & 63, r = e >> 12;
        int hr = h - 1 + r;
        float v = (hr >= 0 && hr <= 63) ? b2f(qkv[((b * 64 + hr) * 64 + w) * 192 + 64 + c]) : 0.f;
        sm[c * 199 + r * 66 + w + 1] = v;
    }
    __syncthreads();

    int head = __builtin_amdgcn_readfirstlane((t >> 6) & 3);  // duplicated across halves
    int pos  = t & 63;
    float q[16];
    const bf16* qrow = qkv + (((b * 64 + h) * 64) + pos) * 192 + head * 16;
#pragma unroll
    for (int d = 0; d < 16; ++d) q[d] = b2f(qrow[d]);

    float a[9];
#pragma unroll
    for (int r = 0; r < 3; ++r)
#pragma unroll
        for (int cxi = 0; cxi < 3; ++cxi) {
            float dot = 0.f;
#pragma unroll
            for (int d = 0; d < 16; ++d)
                dot = fmaf(q[d], sm[(head * 16 + d) * 199 + r * 66 + pos + cxi], dot);
            a[r * 3 + cxi] = dot * 0.25f;   // SCALE = 16^-0.5
        }
    float mx = a[0];
#pragma unroll
    for (int k = 1; k < 9; ++k) mx = fmaxf(mx, a[k]);
    float ssum = 0.f;
#pragma unroll
    for (int k = 0; k < 9; ++k) { a[k] = __expf(a[k] - mx); ssum += a[k]; }
    float inv = 1.f / ssum;
#pragma unroll
    for (int k = 0; k < 9; ++k) a[k] *= inv;
    __syncthreads();

    // reload interior with V (qkv channels 128..191); halo still zero
    for (int e = t; e < 3 * 64 * 64; e += 512) {
        int c = e & 63, w = (e >> 6) & 63, r = e >> 12;
        int hr = h - 1 + r;
        float v = (hr >= 0 && hr <= 63) ? b2f(qkv[((b * 64 + hr) * 64 + w) * 192 + 128 + c]) : 0.f;
        sm[c * 199 + r * 66 + w + 1] = v;
    }
    __syncthreads();

    float o[16];
#pragma unroll
    for (int d = 0; d < 16; ++d) {
        float ov = 0.f;
#pragma unroll
        for (int r = 0; r < 3; ++r)
#pragma unroll
            for (int cxi = 0; cxi < 3; ++cxi)
                ov = fmaf(a[r * 3 + cxi], sm[(head * 16 + d) * 199 + r * 66 + pos + cxi], ov);
        o[d] = ov;
    }
    __syncthreads();
    // os[pos][64] -- only the first half writes (second half is a duplicate)
    if (t < 256) {
#pragma unroll
        for (int d = 0; d < 16; ++d) sm[pos * 65 + head * 16 + d] = o[d];
    }
    __syncthreads();

    int g = __builtin_amdgcn_readfirstlane(t >> 6);  // 0..7 for 8-wide phases
    float acc[8];
#pragma unroll
    for (int ci = 0; ci < 8; ++ci) acc[ci] = ldp(outb, g * 8 + ci, md);
    for (int k = 0; k < 64; ++k) {
        float ov = sm[pos * 65 + k];
        const float* ow = outt + k * 64 + g * 8;
#pragma unroll
        for (int ci = 0; ci < 8; ++ci) acc[ci] = fmaf(ow[ci], ov, acc[ci]);
    }
    int idx = ((b * 64 + h) * 64 + pos) * 64 + g * 8;
    // t = xn + attn_out -> ts region
#pragma unroll
    for (int ci = 0; ci < 8; ++ci)
        sm[4224 + pos * 65 + g * 8 + ci] = xio[idx + ci] + acc[ci];
    __syncthreads();

    // ln2 per token -> ys region
    if (t < 64) {
        float s = 0.f, sq = 0.f;
        for (int c = 0; c < 64; ++c) { float v = sm[4224 + t * 65 + c]; s += v; sq += v * v; }
        float mu = s * (1.f / 64.f);
        float var = sq * (1.f / 64.f) - mu * mu;
        float rs = rsqrtf(fmaxf(var, 0.f) + 1e-5f);
        for (int c = 0; c < 64; ++c) {
            float v = sm[4224 + t * 65 + c];
            sm[8448 + t * 65 + c] = (v - mu) * rs * ldp(ln2w, c, md) + ldp(ln2b, c, md);
        }
    }
    __syncthreads();

    // MLP1 + exact GELU -> hs (os region, dead after proj)
#pragma unroll
    for (int mi = 0; mi < 8; ++mi) acc[mi] = ldp(ff1b, g * 8 + mi, md);
    for (int c = 0; c < 64; ++c) {
        float yv = sm[8448 + pos * 65 + c];
        const float* fw = ff1t + c * 64 + g * 8;
#pragma unroll
        for (int mi = 0; mi < 8; ++mi) acc[mi] = fmaf(fw[mi], yv, acc[mi]);
    }
    __syncthreads();
#pragma unroll
    for (int mi = 0; mi < 8; ++mi) {
        float v = acc[mi];
        sm[pos * 65 + g * 8 + mi] = 0.5f * v * (1.f + erff(v * 0.70710678118654752f));
    }
    __syncthreads();

    // MLP2 + residual + ch0 restore + state/out write
#pragma unroll
    for (int ci = 0; ci < 8; ++ci) acc[ci] = ldp(ff2b, g * 8 + ci, md);
    for (int m = 0; m < 64; ++m) {
        float hv = sm[pos * 65 + m];
        const float* fw = ff2t + m * 64 + g * 8;
#pragma unroll
        for (int ci = 0; ci < 8; ++ci) acc[ci] = fmaf(fw[ci], hv, acc[ci]);
    }
#pragma unroll
    for (int ci = 0; ci < 8; ++ci) {
        float fv = sm[4224 + pos * 65 + g * 8 + ci] + acc[ci];
        if (g == 0 && ci == 0) fv = c0buf[(b * 64 + h) * 64 + pos];  // keep input ch0
        fv = finz(fv);
        xio[idx + ci] = fv;
        if (write_out) {
            if (md) ((float*)dout)[idx + ci] = fv;
            else    ((bf16*)dout)[idx + ci] = __float2bfloat16(fv);
        }
    }
}

// ---------------- launch ----------------

extern "C" void kernel_launch(void* const* d_in, const int* in_sizes, int n_in,
                              void* d_out, int out_size, void* d_ws, size_t ws_size,
                              hipStream_t stream) {
    (void)in_sizes; (void)n_in; (void)out_size; (void)ws_size;
    const void* x     = d_in[0];
    const void* masks = d_in[1];
    const void* p0w   = d_in[2];
    const void* p0b   = d_in[3];
    const void* p1w   = d_in[4];
    const void* p1b   = d_in[5];
    const void* fc0w  = d_in[6];
    const void* fc0b  = d_in[7];
    const void* fc1w  = d_in[8];
    const void* n0w   = d_in[9];
    const void* n0b   = d_in[10];
    const void* ln1w  = d_in[11];
    const void* ln1b  = d_in[12];
    const void* qkvw  = d_in[13];
    const void* outw  = d_in[14];
    const void* outb  = d_in[15];
    const void* ln2w  = d_in[16];
    const void* ln2b  = d_in[17];
    const void* ff1w  = d_in[18];
    const void* ff1b  = d_in[19];
    const void* ff2w  = d_in[20];
    const void* ff2b  = d_in[21];

    // compact workspace layout, ~21.6 MB total.
    char* wsb = (char*)d_ws;
    float* xst    = (float*)(wsb + 0);           //  8,388,608 B  fp32 state (in-place)
    bf16*  hd     = (bf16*) (wsb + 8388608);     // 12,582,912 B region
    bf16*  qkvb   = (bf16*) (wsb + 8388608);     //   (alias of hd)
    float* c0buf  = (float*)(wsb + 20971520);    //    131,072 B
    float* wpk    = (float*)(wsb + 21102592);    //    294,912 B
    float* fc0t   = (float*)(wsb + 21397504);    //     98,304 B
    float* fc1t   = (float*)(wsb + 21495808);    //     32,768 B
    float* qkvt   = (float*)(wsb + 21528576);    //     49,152 B
    float* outt   = (float*)(wsb + 21577728);    //     16,384 B
    float* ff1t   = (float*)(wsb + 21594112);    //     16,384 B
    float* ff2t   = (float*)(wsb + 21610496);    //     16,384 B
    float* accv   = (float*)(wsb + 21626880);    //        384 B
    int*   mflags = (int*)  (wsb + 21627264);    //         16 B

    k_detect<<<1, 256, 0, stream>>>((const unsigned char*)masks,
                                    (const unsigned char*)x, mflags, accv);
    k_cast<<<8192, 256, 0, stream>>>(x, xst, mflags, 2097152);
    k_pack_conv<<<288, 256, 0, stream>>>(p0w, p1w, wpk, mflags);
    k_transpose<<<96, 256, 0, stream>>>(fc0w, fc0t, mflags, 128, 192);
    k_transpose<<<32, 256, 0, stream>>>(fc1w, fc1t, mflags, 64, 128);
    k_transpose<<<48, 256, 0, stream>>>(qkvw, qkvt, mflags, 192, 64);
    k_transpose<<<16, 256, 0, stream>>>(outw, outt, mflags, 64, 64);
    k_transpose<<<16, 256, 0, stream>>>(ff1w, ff1t, mflags, 64, 64);
    k_transpose<<<16, 256, 0, stream>>>(ff2w, ff2t, mflags, 64, 64);

    for (int s = 0; s < NSTEP; ++s) {
        k_perceive<<<512, 512, 0, stream>>>(xst, wpk, fc0t, p0b, p1b, fc0b, mflags, hd, accv, s);
        k_update<<<512, 512, 0, stream>>>(xst, hd, fc1t, n0w, n0b, masks, mflags, accv, c0buf, s);
        k_qkv<<<512, 512, 0, stream>>>(xst, qkvt, ln1w, ln1b, mflags, qkvb);
        k_attn_ff<<<512, 512, 0, stream>>>(qkvb, xst, c0buf, outt, ff1t, ff2t,
                                           outb, ln2w, ln2b, ff1b, ff2b, mflags,
                                           d_out, (s == NSTEP - 1) ? 1 : 0);
    }
}

// Round 6
// 1250.399 us; speedup vs baseline: 1.5353x; 1.3256x over previous
//
#include <hip/hip_runtime.h>
#include <hip/hip_bf16.h>

typedef __hip_bfloat16 bf16;

#define NSTEP 6

static __device__ __forceinline__ float b2f(bf16 v) { return __bfloat162float(v); }

// dtype-dispatched param load: md==0 -> bf16, md==1 -> float32
static __device__ __forceinline__ float ldp(const void* p, int i, int md) {
    return md ? ((const float*)p)[i] : b2f(((const bf16*)p)[i]);
}
static __device__ __forceinline__ float finz(float v) {
    return (v == v && v * 0.0f == 0.0f) ? v : 0.0f;  // non-finite -> 0
}

// 8 consecutive bf16 -> 8 floats (one 16B load)
static __device__ __forceinline__ void ld_bf8(const bf16* p, float* f) {
    union { uint4 u; unsigned short s[8]; } r;
    r.u = *(const uint4*)p;
#pragma unroll
    for (int j = 0; j < 8; ++j) f[j] = __uint_as_float(((unsigned)r.s[j]) << 16);
}
// dtype-dispatched 8-wide param load (i multiple of 8)
static __device__ __forceinline__ void ldp8(const void* p, int i, int md, float* f) {
    if (md) {
        const float* fp = (const float*)p + i;
        float4 a = *(const float4*)fp, b = *(const float4*)(fp + 4);
        f[0]=a.x; f[1]=a.y; f[2]=a.z; f[3]=a.w; f[4]=b.x; f[5]=b.y; f[6]=b.z; f[7]=b.w;
    } else {
        ld_bf8((const bf16*)p + i, f);
    }
}
// pack 8 floats -> uint4 of bf16 (RNE)
static __device__ __forceinline__ uint4 pk_bf8(const float* f) {
    union { uint4 u; unsigned short s[8]; } r;
#pragma unroll
    for (int j = 0; j < 8; ++j) { bf16 h = __float2bfloat16(f[j]); r.s[j] = *(unsigned short*)&h; }
    return r.u;
}

// ---------------- detect / pack / cast kernels ----------------

// flags[0]: masks dtype mode (0 int32, 1 u8, 2 16-bit, 3 f32)
// flags[1]: float-array dtype (0 bf16, 1 f32); also zeroes accv (96 floats)
__global__ void k_detect(const unsigned char* __restrict__ m,
                         const unsigned char* __restrict__ xb,
                         int* __restrict__ flags, float* __restrict__ accv) {
    __shared__ int s3f, sup, slo, sf32;
    int t = threadIdx.x;
    if (t == 0) { s3f = 0; sup = 0; slo = 0; sf32 = 0; }
    if (t < 96) accv[t] = 0.f;
    __syncthreads();
    int l3f = 0, lup = 0, llo = 0, lf = 0;
    for (int i = t; i < 49152; i += 256) {
        unsigned char v = m[i];
        if (v == 0x3F) l3f = 1;
        if ((i & 3) != 0 && v != 0) lup = 1;
        if ((i & 3) < 2 && v != 0) llo = 1;
    }
    for (int i = t * 4 + 1; i < 65536; i += 1024) {
        unsigned char v = xb[i];
        if ((v & 0x7F) > 0x48) lf = 1;
    }
    if (l3f) atomicOr(&s3f, 1);
    if (lup) atomicOr(&sup, 1);
    if (llo) atomicOr(&slo, 1);
    if (lf)  atomicOr(&sf32, 1);
    __syncthreads();
    if (t == 0) {
        int mode;
        if (!s3f && !sup) mode = 0;
        else if (!s3f)    mode = 1;
        else if (slo)     mode = 2;
        else              mode = 3;
        flags[0] = mode;
        flags[1] = sf32;
    }
}

// 8 elements per thread
__global__ void k_cast(const void* __restrict__ in, float* __restrict__ out,
                       const int* __restrict__ mflags, int n8) {
    int md = mflags[1];
    int i = blockIdx.x * 256 + threadIdx.x;
    if (i < n8) {
        float f[8];
        ldp8(in, i * 8, md, f);
#pragma unroll
        for (int j = 0; j < 8; ++j) f[j] = finz(f[j]);
        *(float4*)&out[i * 8]     = make_float4(f[0], f[1], f[2], f[3]);
        *(float4*)&out[i * 8 + 4] = make_float4(f[4], f[5], f[6], f[7]);
    }
}

// out[k*R + r] = in[r*K + k]
__global__ void k_transpose(const void* __restrict__ in, float* __restrict__ out,
                            const int* __restrict__ mflags, int R, int K) {
    int md = mflags[1];
    int i = blockIdx.x * 256 + threadIdx.x;
    if (i < R * K) {
        int k = i / R, r = i % R;
        out[i] = ldp(in, r * K + k, md);
    }
}

// wpk[(i*9+k)*128 + o] : o<64 -> p0_w[o][i][k], else p1_w[o-64][i][k]
__global__ void k_pack_conv(const void* __restrict__ p0, const void* __restrict__ p1,
                            float* __restrict__ out, const int* __restrict__ mflags) {
    int md = mflags[1];
    int i = blockIdx.x * 256 + threadIdx.x;
    if (i < 64 * 9 * 128) {
        int o = i & 127, kidx = i >> 7;
        out[i] = (o < 64) ? ldp(p0, o * 576 + kidx, md) : ldp(p1, (o - 64) * 576 + kidx, md);
    }
}

// ---------------- step kernels ----------------
// grid 512 = B*H rows, 512 threads (8 waves) per block.

// A: perception (2 reflect-pad 3x3 convs) + fc0 + relu -> hd (bf16); partial LN sums
__global__ __launch_bounds__(512) void k_perceive(
    const float* __restrict__ xin, const float* __restrict__ wpk,
    const float* __restrict__ fc0t, const void* __restrict__ p0b,
    const void* __restrict__ p1b, const void* __restrict__ fc0b,
    const int* __restrict__ mflags, bf16* __restrict__ hd,
    float* __restrict__ accv, int step)
{
    __shared__ float sm[12864];   // phase1: x [ch=64][row=3][wp=67] stride 201/67; phase2: p [pos][193]
    int md = mflags[1];
    int bh = blockIdx.x;
    int b = bh >> 6, h = bh & 63;
    int t = threadIdx.x;

    // stage 3 rows of x, float4 loads, scatter to [c][r][wp]
    // padded row P[0..65]: P[j]=x[j-1] for j=1..64, P[0]=x[1], P[65]=x[62]
    for (int e = t; e < 3072; e += 512) {
        int c4 = e & 15, w = (e >> 4) & 63, r = e >> 10;
        int hr = h - 1 + r; hr = hr < 0 ? -hr : (hr > 63 ? 126 - hr : hr);
        float4 v = *(const float4*)&xin[((((b << 6) + hr) << 6) | w) * 64 + c4 * 4];
        const float* vp = (const float*)&v;
#pragma unroll
        for (int j = 0; j < 4; ++j) {
            int base = (c4 * 4 + j) * 201 + r * 67;
            float vv = vp[j];
            sm[base + w + 1] = vv;
            if (w == 1)  sm[base]      = vv;   // reflect left  (P[0]  = x[1])
            if (w == 62) sm[base + 65] = vv;   // reflect right (P[65] = x[62])
        }
    }
    __syncthreads();

    int og  = __builtin_amdgcn_readfirstlane(t >> 6);  // wave-uniform group 0..7
    int pos = t & 63;

    // conv: 16 of the 128 conv outputs per thread (y1:0..63, y2:64..127)
    float acc[16];
#pragma unroll
    for (int oi = 0; oi < 16; ++oi) {
        int oa = og * 16 + oi;
        acc[oi] = (oa < 64) ? ldp(p0b, oa, md) : ldp(p1b, oa - 64, md);
    }
    for (int i = 0; i < 64; ++i) {
        float xv[9];
#pragma unroll
        for (int r = 0; r < 3; ++r)
#pragma unroll
            for (int cxi = 0; cxi < 3; ++cxi)
                xv[r * 3 + cxi] = sm[i * 201 + r * 67 + pos + cxi];
        const float* wp = wpk + (i * 9) * 128 + og * 16;
#pragma unroll
        for (int k = 0; k < 9; ++k) {
#pragma unroll
            for (int oi = 0; oi < 16; ++oi)
                acc[oi] = fmaf(wp[k * 128 + oi], xv[k], acc[oi]);
        }
    }
    // my 8 channels of raw x (center pixel) for the concat
    float xreg[8];
#pragma unroll
    for (int j = 0; j < 8; ++j)
        xreg[j] = sm[(og * 8 + j) * 201 + 67 + pos + 1];
    __syncthreads();

    // build p = [x(64), y1(64), y2(64)] in LDS, [pos][193]
#pragma unroll
    for (int j = 0; j < 8; ++j) sm[pos * 193 + og * 8 + j] = xreg[j];
#pragma unroll
    for (int oi = 0; oi < 16; ++oi) sm[pos * 193 + 64 + og * 16 + oi] = acc[oi];
    __syncthreads();

    // fc0: 16 of 128 hidden outputs per thread, relu, store; LN partials
#pragma unroll
    for (int jj = 0; jj < 16; ++jj) acc[jj] = ldp(fc0b, og * 16 + jj, md);
    for (int kk = 0; kk < 192; ++kk) {
        float pv = sm[pos * 193 + kk];
        const float* fw = fc0t + kk * 128 + og * 16;
#pragma unroll
        for (int jj = 0; jj < 16; ++jj)
            acc[jj] = fmaf(fw[jj], pv, acc[jj]);
    }
    float lsum = 0.f, lsq = 0.f;
    union { uint4 u[2]; unsigned short s[16]; } pk;
#pragma unroll
    for (int jj = 0; jj < 16; ++jj) {
        bf16 hv = __float2bfloat16(fmaxf(acc[jj], 0.f));
        pk.s[jj] = *(unsigned short*)&hv;
        float vr = b2f(hv);          // stats from the rounded value we store
        lsum += vr; lsq += vr * vr;
    }
    bf16* hrow = hd + ((((b << 6) + h) << 6) + pos) * 128 + og * 16;
    *(uint4*)hrow       = pk.u[0];
    *(uint4*)(hrow + 8) = pk.u[1];
    // wave-level shuffle reduction, then cross-wave via LDS
#pragma unroll
    for (int off = 32; off > 0; off >>= 1) {
        lsum += __shfl_down(lsum, off, 64);
        lsq  += __shfl_down(lsq,  off, 64);
    }
    __syncthreads();
    if ((t & 63) == 0) { sm[og] = lsum; sm[16 + og] = lsq; }
    __syncthreads();
    if (t == 0) {
        float a = 0.f, q = 0.f;
#pragma unroll
        for (int w = 0; w < 8; ++w) { a += sm[w]; q += sm[16 + w]; }
        atomicAdd(&accv[step * 16 + b * 2],     a);
        atomicAdd(&accv[step * 16 + b * 2 + 1], q);
    }
}

// B+C1 fused: global LN0 + fc1 + mask + residual (in-place on x) then
// per-token LN1 + qkv projection. Keeps xn in LDS between the two halves.
__global__ __launch_bounds__(512) void k_update_qkv(
    float* __restrict__ xio, const bf16* __restrict__ hd,
    const float* __restrict__ fc1t, const void* __restrict__ n0w,
    const void* __restrict__ n0b, const void* __restrict__ mraw,
    const int* __restrict__ mflags, const float* __restrict__ accv,
    float* __restrict__ c0buf, const float* __restrict__ qkvt,
    const void* __restrict__ ln1w, const void* __restrict__ ln1b,
    bf16* __restrict__ qkv, int step)
{
    __shared__ float hdn[64 * 129];  // 8256 floats
    __shared__ float ys[64 * 65];    // 4160 floats
    int md = mflags[1];
    int bh = blockIdx.x;
    int b = bh >> 6, h = bh & 63;
    int t = threadIdx.x;
    const float invN = 1.f / 524288.f;
    float mean = accv[step * 16 + b * 2] * invN;
    float var  = accv[step * 16 + b * 2 + 1] * invN - mean * mean;
    float rstd = rsqrtf(fmaxf(var, 0.f) + 1e-5f);

    const bf16* hrow = hd + ((b * 64 + h) * 64) * 128;
    for (int e = t; e < 1024; e += 512) {           // 8 elements per chunk
        int pos = e >> 4, j8 = (e & 15) * 8;
        float hv[8], wv[8], bv[8];
        ld_bf8(hrow + pos * 128 + j8, hv);
        int ni = (h * 64 + pos) * 128 + j8;
        ldp8(n0w, ni, md, wv);
        ldp8(n0b, ni, md, bv);
#pragma unroll
        for (int j = 0; j < 8; ++j)
            hdn[pos * 129 + j8 + j] = (hv[j] - mean) * rstd * wv[j] + bv[j];
    }
    __syncthreads();

    int cg  = __builtin_amdgcn_readfirstlane(t >> 6);   // 0..7
    int pos = t & 63;
    float acc[8];
#pragma unroll
    for (int ci = 0; ci < 8; ++ci) acc[ci] = 0.f;
    for (int j = 0; j < 128; ++j) {
        float hv = hdn[pos * 129 + j];
        const float* fw = fc1t + j * 64 + cg * 8;
#pragma unroll
        for (int ci = 0; ci < 8; ++ci) acc[ci] = fmaf(fw[ci], hv, acc[ci]);
    }
    int mmode = mflags[0];
    int midx = ((step * 8 + b) * 64 + h) * 64 + pos;
    int m;
    if (mmode == 0)      m = ((const int*)mraw)[midx] != 0;
    else if (mmode == 1) m = ((const unsigned char*)mraw)[midx] != 0;
    else if (mmode == 2) m = ((const unsigned short*)mraw)[midx] != 0;
    else                 m = ((const float*)mraw)[midx] != 0.0f;

    int idx = ((b * 64 + h) * 64 + pos) * 64 + cg * 8;
    float4 x0 = *(const float4*)&xio[idx];
    float4 x1 = *(const float4*)&xio[idx + 4];
    float xv[8] = {x0.x, x0.y, x0.z, x0.w, x1.x, x1.y, x1.z, x1.w};
    if (cg == 0) c0buf[(b * 64 + h) * 64 + pos] = xv[0];  // pre-update ch0
    float xn[8];
#pragma unroll
    for (int ci = 0; ci < 8; ++ci) {
        xn[ci] = finz(m ? (xv[ci] + acc[ci]) : xv[ci]);
        ys[pos * 65 + cg * 8 + ci] = xn[ci];
    }
    *(float4*)&xio[idx]     = make_float4(xn[0], xn[1], xn[2], xn[3]);
    *(float4*)&xio[idx + 4] = make_float4(xn[4], xn[5], xn[6], xn[7]);
    __syncthreads();

    // ln1 per token, in place on ys
    if (t < 64) {
        float s = 0.f, sq = 0.f;
        for (int c = 0; c < 64; ++c) { float v = ys[t * 65 + c]; s += v; sq += v * v; }
        float mu = s * (1.f / 64.f);
        float vr = sq * (1.f / 64.f) - mu * mu;
        float rs = rsqrtf(fmaxf(vr, 0.f) + 1e-5f);
        for (int c = 0; c < 64; ++c) {
            float v = ys[t * 65 + c];
            ys[t * 65 + c] = (v - mu) * rs * ldp(ln1w, c, md) + ldp(ln1b, c, md);
        }
    }
    __syncthreads();

    // qkv projection: 24 outputs per thread
    float a2[24];
#pragma unroll
    for (int oi = 0; oi < 24; ++oi) a2[oi] = 0.f;
    for (int c = 0; c < 64; ++c) {
        float yv = ys[pos * 65 + c];
        const float* qw = qkvt + c * 192 + cg * 24;
#pragma unroll
        for (int oi = 0; oi < 24; ++oi) a2[oi] = fmaf(qw[oi], yv, a2[oi]);
    }
    union { uint4 u[3]; unsigned short s[24]; } pq;
#pragma unroll
    for (int oi = 0; oi < 24; ++oi) {
        bf16 hv = __float2bfloat16(a2[oi]);
        pq.s[oi] = *(unsigned short*)&hv;
    }
    uint4* qrow = (uint4*)(qkv + (((b * 64 + h) * 64) + pos) * 192 + cg * 24);
    qrow[0] = pq.u[0]; qrow[1] = pq.u[1]; qrow[2] = pq.u[2];
}

// C2+D fused: 3x3 zero-padded local attention + out-proj + residual (t),
// then ln2 + GELU MLP + residual + ch0 restore; in-place state, optional out.
__global__ __launch_bounds__(512) void k_attn_ff(
    const bf16* __restrict__ qkv, float* __restrict__ xio,
    const float* __restrict__ c0buf, const float* __restrict__ outt,
    const float* __restrict__ ff1t, const float* __restrict__ ff2t,
    const void* __restrict__ outb, const void* __restrict__ ln2w,
    const void* __restrict__ ln2b, const void* __restrict__ ff1b,
    const void* __restrict__ ff2b, const int* __restrict__ mflags,
    void* __restrict__ dout, int write_out)
{
    // region map (floats): [0,12736) KV tiles (stride 199/66), then
    // os=[0,4160) o-frags / later hs; ts=[4224,8384); ys=[8448,12608)
    __shared__ float sm[12736];
    int md = mflags[1];
    int bh = blockIdx.x;
    int b = bh >> 6, h = bh & 63;
    int t = threadIdx.x;

    // zero halos (stay zero through K and V phases)
    if (t < 192) {
        int c = t & 63, r = t >> 6;
        sm[c * 199 + r * 66]      = 0.f;
        sm[c * 199 + r * 66 + 65] = 0.f;
    }
    // K staging: bf16x8 vector loads, scatter to [c][r][wp]
    for (int e = t; e < 1536; e += 512) {
        int c8 = (e & 7) * 8, w = (e >> 3) & 63, r = e >> 9;
        int hr = h - 1 + r;
        float f[8];
        if (hr >= 0 && hr <= 63) {
            ld_bf8(qkv + ((b * 64 + hr) * 64 + w) * 192 + 64 + c8, f);
        } else {
#pragma unroll
            for (int j = 0; j < 8; ++j) f[j] = 0.f;
        }
#pragma unroll
        for (int j = 0; j < 8; ++j) sm[(c8 + j) * 199 + r * 66 + w + 1] = f[j];
    }
    __syncthreads();

    int head = __builtin_amdgcn_readfirstlane((t >> 6) & 3);  // duplicated across halves
    int pos  = t & 63;
    float q[16];
    {
        const bf16* qr = qkv + (((b * 64 + h) * 64) + pos) * 192 + head * 16;
        ld_bf8(qr, q); ld_bf8(qr + 8, q + 8);
    }

    float a[9];
#pragma unroll
    for (int r = 0; r < 3; ++r)
#pragma unroll
        for (int cxi = 0; cxi < 3; ++cxi) {
            float dot = 0.f;
#pragma unroll
            for (int d = 0; d < 16; ++d)
                dot = fmaf(q[d], sm[(head * 16 + d) * 199 + r * 66 + pos + cxi], dot);
            a[r * 3 + cxi] = dot * 0.25f;   // SCALE = 16^-0.5
        }
    float mx = a[0];
#pragma unroll
    for (int k = 1; k < 9; ++k) mx = fmaxf(mx, a[k]);
    float ssum = 0.f;
#pragma unroll
    for (int k = 0; k < 9; ++k) { a[k] = __expf(a[k] - mx); ssum += a[k]; }
    float inv = 1.f / ssum;
#pragma unroll
    for (int k = 0; k < 9; ++k) a[k] *= inv;
    __syncthreads();

    // V staging (channels 128..191); halo still zero
    for (int e = t; e < 1536; e += 512) {
        int c8 = (e & 7) * 8, w = (e >> 3) & 63, r = e >> 9;
        int hr = h - 1 + r;
        float f[8];
        if (hr >= 0 && hr <= 63) {
            ld_bf8(qkv + ((b * 64 + hr) * 64 + w) * 192 + 128 + c8, f);
        } else {
#pragma unroll
            for (int j = 0; j < 8; ++j) f[j] = 0.f;
        }
#pragma unroll
        for (int j = 0; j < 8; ++j) sm[(c8 + j) * 199 + r * 66 + w + 1] = f[j];
    }
    __syncthreads();

    float o[16];
#pragma unroll
    for (int d = 0; d < 16; ++d) {
        float ov = 0.f;
#pragma unroll
        for (int r = 0; r < 3; ++r)
#pragma unroll
            for (int cxi = 0; cxi < 3; ++cxi)
                ov = fmaf(a[r * 3 + cxi], sm[(head * 16 + d) * 199 + r * 66 + pos + cxi], ov);
        o[d] = ov;
    }
    __syncthreads();
    // os[pos][64] -- only the first half writes (second half duplicates)
    if (t < 256) {
#pragma unroll
        for (int d = 0; d < 16; ++d) sm[pos * 65 + head * 16 + d] = o[d];
    }
    __syncthreads();

    int g = __builtin_amdgcn_readfirstlane(t >> 6);  // 0..7 for 8-wide phases
    float acc[8];
#pragma unroll
    for (int ci = 0; ci < 8; ++ci) acc[ci] = ldp(outb, g * 8 + ci, md);
    for (int k = 0; k < 64; ++k) {
        float ov = sm[pos * 65 + k];
        const float* ow = outt + k * 64 + g * 8;
#pragma unroll
        for (int ci = 0; ci < 8; ++ci) acc[ci] = fmaf(ow[ci], ov, acc[ci]);
    }
    int idx = ((b * 64 + h) * 64 + pos) * 64 + g * 8;
    {
        float4 x0 = *(const float4*)&xio[idx];
        float4 x1 = *(const float4*)&xio[idx + 4];
        const float* xp = (const float*)&x0;
        float* ts = &sm[4224 + pos * 65 + g * 8];
#pragma unroll
        for (int ci = 0; ci < 4; ++ci) ts[ci] = xp[ci] + acc[ci];
        xp = (const float*)&x1;
#pragma unroll
        for (int ci = 0; ci < 4; ++ci) ts[4 + ci] = xp[ci] + acc[4 + ci];
    }
    __syncthreads();

    // ln2 per token -> ys region
    if (t < 64) {
        float s = 0.f, sq = 0.f;
        for (int c = 0; c < 64; ++c) { float v = sm[4224 + t * 65 + c]; s += v; sq += v * v; }
        float mu = s * (1.f / 64.f);
        float vr = sq * (1.f / 64.f) - mu * mu;
        float rs = rsqrtf(fmaxf(vr, 0.f) + 1e-5f);
        for (int c = 0; c < 64; ++c) {
            float v = sm[4224 + t * 65 + c];
            sm[8448 + t * 65 + c] = (v - mu) * rs * ldp(ln2w, c, md) + ldp(ln2b, c, md);
        }
    }
    __syncthreads();

    // MLP1 + exact GELU -> hs (os region, dead after proj)
#pragma unroll
    for (int mi = 0; mi < 8; ++mi) acc[mi] = ldp(ff1b, g * 8 + mi, md);
    for (int c = 0; c < 64; ++c) {
        float yv = sm[8448 + pos * 65 + c];
        const float* fw = ff1t + c * 64 + g * 8;
#pragma unroll
        for (int mi = 0; mi < 8; ++mi) acc[mi] = fmaf(fw[mi], yv, acc[mi]);
    }
    __syncthreads();
#pragma unroll
    for (int mi = 0; mi < 8; ++mi) {
        float v = acc[mi];
        sm[pos * 65 + g * 8 + mi] = 0.5f * v * (1.f + erff(v * 0.70710678118654752f));
    }
    __syncthreads();

    // MLP2 + residual + ch0 restore + state/out write
#pragma unroll
    for (int ci = 0; ci < 8; ++ci) acc[ci] = ldp(ff2b, g * 8 + ci, md);
    for (int m = 0; m < 64; ++m) {
        float hv = sm[pos * 65 + m];
        const float* fw = ff2t + m * 64 + g * 8;
#pragma unroll
        for (int ci = 0; ci < 8; ++ci) acc[ci] = fmaf(fw[ci], hv, acc[ci]);
    }
    float fv[8];
#pragma unroll
    for (int ci = 0; ci < 8; ++ci) {
        float v = sm[4224 + pos * 65 + g * 8 + ci] + acc[ci];
        if (g == 0 && ci == 0) v = c0buf[(b * 64 + h) * 64 + pos];  // keep input ch0
        fv[ci] = finz(v);
    }
    *(float4*)&xio[idx]     = make_float4(fv[0], fv[1], fv[2], fv[3]);
    *(float4*)&xio[idx + 4] = make_float4(fv[4], fv[5], fv[6], fv[7]);
    if (write_out) {
        if (md) {
            *(float4*)&((float*)dout)[idx]     = make_float4(fv[0], fv[1], fv[2], fv[3]);
            *(float4*)&((float*)dout)[idx + 4] = make_float4(fv[4], fv[5], fv[6], fv[7]);
        } else {
            *(uint4*)&((bf16*)dout)[idx] = pk_bf8(fv);
        }
    }
}

// ---------------- launch ----------------

extern "C" void kernel_launch(void* const* d_in, const int* in_sizes, int n_in,
                              void* d_out, int out_size, void* d_ws, size_t ws_size,
                              hipStream_t stream) {
    (void)in_sizes; (void)n_in; (void)out_size; (void)ws_size;
    const void* x     = d_in[0];
    const void* masks = d_in[1];
    const void* p0w   = d_in[2];
    const void* p0b   = d_in[3];
    const void* p1w   = d_in[4];
    const void* p1b   = d_in[5];
    const void* fc0w  = d_in[6];
    const void* fc0b  = d_in[7];
    const void* fc1w  = d_in[8];
    const void* n0w   = d_in[9];
    const void* n0b   = d_in[10];
    const void* ln1w  = d_in[11];
    const void* ln1b  = d_in[12];
    const void* qkvw  = d_in[13];
    const void* outw  = d_in[14];
    const void* outb  = d_in[15];
    const void* ln2w  = d_in[16];
    const void* ln2b  = d_in[17];
    const void* ff1w  = d_in[18];
    const void* ff1b  = d_in[19];
    const void* ff2w  = d_in[20];
    const void* ff2b  = d_in[21];

    // compact workspace layout, ~21.6 MB total.
    char* wsb = (char*)d_ws;
    float* xst    = (float*)(wsb + 0);           //  8,388,608 B  fp32 state (in-place)
    bf16*  hd     = (bf16*) (wsb + 8388608);     // 12,582,912 B region
    bf16*  qkvb   = (bf16*) (wsb + 8388608);     //   (alias of hd)
    float* c0buf  = (float*)(wsb + 20971520);    //    131,072 B
    float* wpk    = (float*)(wsb + 21102592);    //    294,912 B
    float* fc0t   = (float*)(wsb + 21397504);    //     98,304 B
    float* fc1t   = (float*)(wsb + 21495808);    //     32,768 B
    float* qkvt   = (float*)(wsb + 21528576);    //     49,152 B
    float* outt   = (float*)(wsb + 21577728);    //     16,384 B
    float* ff1t   = (float*)(wsb + 21594112);    //     16,384 B
    float* ff2t   = (float*)(wsb + 21610496);    //     16,384 B
    float* accv   = (float*)(wsb + 21626880);    //        384 B
    int*   mflags = (int*)  (wsb + 21627264);    //         16 B

    k_detect<<<1, 256, 0, stream>>>((const unsigned char*)masks,
                                    (const unsigned char*)x, mflags, accv);
    k_cast<<<1024, 256, 0, stream>>>(x, xst, mflags, 262144);
    k_pack_conv<<<288, 256, 0, stream>>>(p0w, p1w, wpk, mflags);
    k_transpose<<<96, 256, 0, stream>>>(fc0w, fc0t, mflags, 128, 192);
    k_transpose<<<32, 256, 0, stream>>>(fc1w, fc1t, mflags, 64, 128);
    k_transpose<<<48, 256, 0, stream>>>(qkvw, qkvt, mflags, 192, 64);
    k_transpose<<<16, 256, 0, stream>>>(outw, outt, mflags, 64, 64);
    k_transpose<<<16, 256, 0, stream>>>(ff1w, ff1t, mflags, 64, 64);
    k_transpose<<<16, 256, 0, stream>>>(ff2w, ff2t, mflags, 64, 64);

    for (int s = 0; s < NSTEP; ++s) {
        k_perceive<<<512, 512, 0, stream>>>(xst, wpk, fc0t, p0b, p1b, fc0b, mflags, hd, accv, s);
        k_update_qkv<<<512, 512, 0, stream>>>(xst, hd, fc1t, n0w, n0b, masks, mflags, accv,
                                              c0buf, qkvt, ln1w, ln1b, qkvb, s);
        k_attn_ff<<<512, 512, 0, stream>>>(qkvb, xst, c0buf, outt, ff1t, ff2t,
                                           outb, ln2w, ln2b, ff1b, ff2b, mflags,
                                           d_out, (s == NSTEP - 1) ? 1 : 0);
    }
}

// Round 7
// 953.028 us; speedup vs baseline: 2.0143x; 1.3120x over previous
//
#include <hip/hip_runtime.h>
#include <hip/hip_bf16.h>

typedef __hip_bfloat16 bf16;
typedef __attribute__((ext_vector_type(8))) short bf16x8;
typedef __attribute__((ext_vector_type(4))) float f32x4;

#define NSTEP 6

static __device__ __forceinline__ float b2f(bf16 v) { return __bfloat162float(v); }

// dtype-dispatched param load: md==0 -> bf16, md==1 -> float32
static __device__ __forceinline__ float ldp(const void* p, int i, int md) {
    return md ? ((const float*)p)[i] : b2f(((const bf16*)p)[i]);
}
static __device__ __forceinline__ float finz(float v) {
    return (v == v && v * 0.0f == 0.0f) ? v : 0.0f;  // non-finite -> 0
}
static __device__ __forceinline__ unsigned short f2bfu(float v) {
    bf16 h = __float2bfloat16(v);
    return *(unsigned short*)&h;
}

// 8 consecutive bf16 -> 8 floats (one 16B load)
static __device__ __forceinline__ void ld_bf8(const bf16* p, float* f) {
    union { uint4 u; unsigned short s[8]; } r;
    r.u = *(const uint4*)p;
#pragma unroll
    for (int j = 0; j < 8; ++j) f[j] = __uint_as_float(((unsigned)r.s[j]) << 16);
}
// dtype-dispatched 8-wide param load (i multiple of 8)
static __device__ __forceinline__ void ldp8(const void* p, int i, int md, float* f) {
    if (md) {
        const float* fp = (const float*)p + i;
        float4 a = *(const float4*)fp, b = *(const float4*)(fp + 4);
        f[0]=a.x; f[1]=a.y; f[2]=a.z; f[3]=a.w; f[4]=b.x; f[5]=b.y; f[6]=b.z; f[7]=b.w;
    } else {
        ld_bf8((const bf16*)p + i, f);
    }
}
// pack 8 floats -> uint4 of bf16 (RNE)
static __device__ __forceinline__ uint4 pk_bf8(const float* f) {
    union { uint4 u; unsigned short s[8]; } r;
#pragma unroll
    for (int j = 0; j < 8; ++j) r.s[j] = f2bfu(f[j]);
    return r.u;
}

// ---------------- detect / pack / cast kernels ----------------

// flags[0]: masks dtype mode (0 int32, 1 u8, 2 16-bit, 3 f32)
// flags[1]: float-array dtype (0 bf16, 1 f32); also zeroes accv (96 floats)
// vectorized: uint4 scans (independent 16B loads, not serial byte loads)
__global__ void k_detect(const uint4* __restrict__ m4,
                         const uint4* __restrict__ x4,
                         int* __restrict__ flags, float* __restrict__ accv) {
    __shared__ int s3f, sup, slo, sf32;
    int t = threadIdx.x;
    if (t == 0) { s3f = 0; sup = 0; slo = 0; sf32 = 0; }
    if (t < 96) accv[t] = 0.f;
    __syncthreads();
    int l3f = 0, lup = 0, llo = 0, lf = 0;
    // masks: 49152 bytes = 3072 uint4
    for (int i = t; i < 3072; i += 256) {
        uint4 v = m4[i];
        const unsigned* d = (const unsigned*)&v;
#pragma unroll
        for (int j = 0; j < 4; ++j) {
            unsigned w = d[j];
            unsigned x3f = w ^ 0x3F3F3F3Fu;                       // any byte == 0x3F?
            if ((x3f - 0x01010101u) & ~x3f & 0x80808080u) l3f = 1;
            if (w & 0xFFFFFF00u) lup = 1;
            if (w & 0x0000FFFFu) llo = 1;
        }
    }
    // x: 65536 bytes = 4096 uint4; test byte at offset 1 of each dword
    for (int i = t; i < 4096; i += 256) {
        uint4 v = x4[i];
        const unsigned* d = (const unsigned*)&v;
#pragma unroll
        for (int j = 0; j < 4; ++j) {
            unsigned bb = (d[j] >> 8) & 0x7Fu;
            if (bb > 0x48u) lf = 1;
        }
    }
    if (l3f) atomicOr(&s3f, 1);
    if (lup) atomicOr(&sup, 1);
    if (llo) atomicOr(&slo, 1);
    if (lf)  atomicOr(&sf32, 1);
    __syncthreads();
    if (t == 0) {
        int mode;
        if (!s3f && !sup) mode = 0;
        else if (!s3f)    mode = 1;
        else if (slo)     mode = 2;
        else              mode = 3;
        flags[0] = mode;
        flags[1] = sf32;
    }
}

// 8 elements per thread
__global__ void k_cast(const void* __restrict__ in, float* __restrict__ out,
                       const int* __restrict__ mflags, int n8) {
    int md = mflags[1];
    int i = blockIdx.x * 256 + threadIdx.x;
    if (i < n8) {
        float f[8];
        ldp8(in, i * 8, md, f);
#pragma unroll
        for (int j = 0; j < 8; ++j) f[j] = finz(f[j]);
        *(float4*)&out[i * 8]     = make_float4(f[0], f[1], f[2], f[3]);
        *(float4*)&out[i * 8 + 4] = make_float4(f[4], f[5], f[6], f[7]);
    }
}

// out[k*R + r] = in[r*K + k]  (f32 packs for the non-MFMA kernels)
__global__ void k_transpose(const void* __restrict__ in, float* __restrict__ out,
                            const int* __restrict__ mflags, int R, int K) {
    int md = mflags[1];
    int i = blockIdx.x * 256 + threadIdx.x;
    if (i < R * K) {
        int k = i / R, r = i % R;
        out[i] = ldp(in, r * K + k, md);
    }
}

// bt1[o][k] bf16, k = (ky*3+kx)*64 + i ; o<64 -> p0_w, else p1_w ([O][I][3][3])
__global__ void k_pack_bt1(const void* __restrict__ p0, const void* __restrict__ p1,
                           short* __restrict__ out, const int* __restrict__ mflags) {
    int md = mflags[1];
    int i = blockIdx.x * 256 + threadIdx.x;
    if (i < 128 * 576) {
        int o = i / 576, k = i % 576;
        int kk = k >> 6, ii = k & 63;
        float v = (o < 64) ? ldp(p0, o * 576 + ii * 9 + kk, md)
                           : ldp(p1, (o - 64) * 576 + ii * 9 + kk, md);
        out[i] = (short)f2bfu(v);
    }
}

// fc0 weights straight cast to bf16, row-major [128][192]
__global__ void k_pack_fc0(const void* __restrict__ w, short* __restrict__ out,
                           const int* __restrict__ mflags) {
    int md = mflags[1];
    int i = blockIdx.x * 256 + threadIdx.x;
    if (i < 128 * 192) out[i] = (short)f2bfu(ldp(w, i, md));
}

// ---------------- step kernels ----------------
// grid 512 = B*H rows, 512 threads (8 waves) per block.

// A (MFMA): conv-as-implicit-GEMM [64x128x576] + fc0 GEMM [64x128x192], bf16
// inputs, fp32 accum. xpad[3][66][72] bf16: A-frag = one ds_read_b128 (channel-
// contiguous, 72-pad for balanced banks). Wave og owns 2 m-tiles x 2 n-tiles.
__global__ __launch_bounds__(512) void k_perceive(
    const float* __restrict__ xin, const short* __restrict__ bt1,
    const short* __restrict__ fc0s, const void* __restrict__ p0b,
    const void* __restrict__ p1b, const void* __restrict__ fc0b,
    const int* __restrict__ mflags, bf16* __restrict__ hd,
    float* __restrict__ accv, int step)
{
    __shared__ __align__(16) short xpad_s[3 * 66 * 72];   // 28512 B
    __shared__ __align__(16) short P_s[64 * 200];          // 25600 B ([m][x64|y1 64|y2 64] +pad)
    __shared__ float red[32];
    int md = mflags[1];
    int bh = blockIdx.x;
    int b = bh >> 6, h = bh & 63;
    int t = threadIdx.x;

    // stage 3 reflected rows of x as bf16; also P x-center (r==1)
    for (int e = t; e < 1536; e += 512) {
        int c8 = e & 7, w = (e >> 3) & 63, r = e >> 9;
        int hr = h - 1 + r; hr = hr < 0 ? -hr : (hr > 63 ? 126 - hr : hr);
        const float* src = xin + ((((b << 6) + hr) << 6) | w) * 64 + c8 * 8;
        float f[8];
        float4 v0 = *(const float4*)src, v1 = *(const float4*)(src + 4);
        f[0]=v0.x; f[1]=v0.y; f[2]=v0.z; f[3]=v0.w; f[4]=v1.x; f[5]=v1.y; f[6]=v1.z; f[7]=v1.w;
        uint4 pv = pk_bf8(f);
        *(uint4*)&xpad_s[((r * 66) + w + 1) * 72 + c8 * 8] = pv;
        if (r == 1) *(uint4*)&P_s[w * 200 + c8 * 8] = pv;
    }
    // w-halos: P[0]=x[1], P[65]=x[62] (reflect)
    if (t < 48) {
        int c8 = t & 7, side = (t >> 3) & 1, r = t >> 4;
        int hr = h - 1 + r; hr = hr < 0 ? -hr : (hr > 63 ? 126 - hr : hr);
        int wsrc = side ? 62 : 1, wp = side ? 65 : 0;
        const float* src = xin + ((((b << 6) + hr) << 6) | wsrc) * 64 + c8 * 8;
        float f[8];
        float4 v0 = *(const float4*)src, v1 = *(const float4*)(src + 4);
        f[0]=v0.x; f[1]=v0.y; f[2]=v0.z; f[3]=v0.w; f[4]=v1.x; f[5]=v1.y; f[6]=v1.z; f[7]=v1.w;
        *(uint4*)&xpad_s[((r * 66) + wp) * 72 + c8 * 8] = pk_bf8(f);
    }
    __syncthreads();

    int og  = __builtin_amdgcn_readfirstlane(t >> 6);  // 0..7
    int l   = t & 63, nl = l & 15, q = l >> 4;
    int mt0 = (og & 1) * 2;            // m-tiles {mt0, mt0+1}
    int nt0 = (og >> 1) * 2;           // n-tiles {nt0, nt0+1}
    int o0  = nt0 * 16 + nl, o1 = o0 + 16;

    f32x4 acc[2][2];
#pragma unroll
    for (int i = 0; i < 2; ++i)
#pragma unroll
        for (int j = 0; j < 2; ++j) acc[i][j] = (f32x4){0.f, 0.f, 0.f, 0.f};

    // GEMM1: conv. K = 576 = 18 k-tiles of 32 (k = (ky*3+kx)*64 + cin)
    for (int kt = 0; kt < 18; ++kt) {
        int kk = kt >> 1, c0 = (kt & 1) << 5;
        int r = kk / 3, cxi = kk - r * 3;
        bf16x8 b0 = *(const bf16x8*)(bt1 + o0 * 576 + kt * 32 + q * 8);
        bf16x8 b1 = *(const bf16x8*)(bt1 + o1 * 576 + kt * 32 + q * 8);
        bf16x8 a0 = *(const bf16x8*)&xpad_s[((r * 66) + mt0 * 16 + nl + cxi) * 72 + c0 + q * 8];
        bf16x8 a1 = *(const bf16x8*)&xpad_s[((r * 66) + mt0 * 16 + 16 + nl + cxi) * 72 + c0 + q * 8];
        acc[0][0] = __builtin_amdgcn_mfma_f32_16x16x32_bf16(a0, b0, acc[0][0], 0, 0, 0);
        acc[0][1] = __builtin_amdgcn_mfma_f32_16x16x32_bf16(a0, b1, acc[0][1], 0, 0, 0);
        acc[1][0] = __builtin_amdgcn_mfma_f32_16x16x32_bf16(a1, b0, acc[1][0], 0, 0, 0);
        acc[1][1] = __builtin_amdgcn_mfma_f32_16x16x32_bf16(a1, b1, acc[1][1], 0, 0, 0);
    }
    // epilogue: + conv bias, write into P cols 64..191 (C/D: row=q*4+reg, col=nl)
    {
        float bias0 = (o0 < 64) ? ldp(p0b, o0, md) : ldp(p1b, o0 - 64, md);
        float bias1 = (o1 < 64) ? ldp(p0b, o1, md) : ldp(p1b, o1 - 64, md);
#pragma unroll
        for (int i = 0; i < 2; ++i)
#pragma unroll
            for (int j = 0; j < 2; ++j) {
                int oo = j ? o1 : o0;
                float bb = j ? bias1 : bias0;
#pragma unroll
                for (int r2 = 0; r2 < 4; ++r2) {
                    int m = (mt0 + i) * 16 + q * 4 + r2;
                    P_s[m * 200 + 64 + oo] = (short)f2bfu(acc[i][j][r2] + bb);
                }
            }
    }
    __syncthreads();

    // GEMM2: fc0. K = 192 = 6 k-tiles
#pragma unroll
    for (int i = 0; i < 2; ++i)
#pragma unroll
        for (int j = 0; j < 2; ++j) acc[i][j] = (f32x4){0.f, 0.f, 0.f, 0.f};
    for (int kt = 0; kt < 6; ++kt) {
        bf16x8 b0 = *(const bf16x8*)(fc0s + o0 * 192 + kt * 32 + q * 8);
        bf16x8 b1 = *(const bf16x8*)(fc0s + o1 * 192 + kt * 32 + q * 8);
        bf16x8 a0 = *(const bf16x8*)&P_s[(mt0 * 16 + nl) * 200 + kt * 32 + q * 8];
        bf16x8 a1 = *(const bf16x8*)&P_s[(mt0 * 16 + 16 + nl) * 200 + kt * 32 + q * 8];
        acc[0][0] = __builtin_amdgcn_mfma_f32_16x16x32_bf16(a0, b0, acc[0][0], 0, 0, 0);
        acc[0][1] = __builtin_amdgcn_mfma_f32_16x16x32_bf16(a0, b1, acc[0][1], 0, 0, 0);
        acc[1][0] = __builtin_amdgcn_mfma_f32_16x16x32_bf16(a1, b0, acc[1][0], 0, 0, 0);
        acc[1][1] = __builtin_amdgcn_mfma_f32_16x16x32_bf16(a1, b1, acc[1][1], 0, 0, 0);
    }
    // epilogue: + fc0 bias, relu, store hd (bf16), LN partial sums (rounded vals)
    float lsum = 0.f, lsq = 0.f;
    {
        float fb0 = ldp(fc0b, o0, md), fb1 = ldp(fc0b, o1, md);
#pragma unroll
        for (int i = 0; i < 2; ++i)
#pragma unroll
            for (int j = 0; j < 2; ++j) {
                int oo = j ? o1 : o0;
                float bb = j ? fb1 : fb0;
#pragma unroll
                for (int r2 = 0; r2 < 4; ++r2) {
                    int m = (mt0 + i) * 16 + q * 4 + r2;
                    float v = fmaxf(acc[i][j][r2] + bb, 0.f);
                    unsigned short hu = f2bfu(v);
                    hd[((bh << 6) + m) * 128 + oo] = *(bf16*)&hu;
                    float vr = __uint_as_float(((unsigned)hu) << 16);
                    lsum += vr; lsq += vr * vr;
                }
            }
    }
#pragma unroll
    for (int off = 32; off > 0; off >>= 1) {
        lsum += __shfl_down(lsum, off, 64);
        lsq  += __shfl_down(lsq,  off, 64);
    }
    if (l == 0) { red[og] = lsum; red[16 + og] = lsq; }
    __syncthreads();
    if (t == 0) {
        float a = 0.f, s2 = 0.f;
#pragma unroll
        for (int w = 0; w < 8; ++w) { a += red[w]; s2 += red[16 + w]; }
        atomicAdd(&accv[step * 16 + b * 2],     a);
        atomicAdd(&accv[step * 16 + b * 2 + 1], s2);
    }
}

// B+C1 fused: global LN0 + fc1 + mask + residual (in-place on x) then
// per-token LN1 + qkv projection. Keeps xn in LDS between the two halves.
__global__ __launch_bounds__(512) void k_update_qkv(
    float* __restrict__ xio, const bf16* __restrict__ hd,
    const float* __restrict__ fc1t, const void* __restrict__ n0w,
    const void* __restrict__ n0b, const void* __restrict__ mraw,
    const int* __restrict__ mflags, const float* __restrict__ accv,
    float* __restrict__ c0buf, const float* __restrict__ qkvt,
    const void* __restrict__ ln1w, const void* __restrict__ ln1b,
    bf16* __restrict__ qkv, int step)
{
    __shared__ float hdn[64 * 129];
    __shared__ float ys[64 * 65];
    int md = mflags[1];
    int bh = blockIdx.x;
    int b = bh >> 6, h = bh & 63;
    int t = threadIdx.x;
    const float invN = 1.f / 524288.f;
    float mean = accv[step * 16 + b * 2] * invN;
    float var  = accv[step * 16 + b * 2 + 1] * invN - mean * mean;
    float rstd = rsqrtf(fmaxf(var, 0.f) + 1e-5f);

    const bf16* hrow = hd + ((b * 64 + h) * 64) * 128;
    for (int e = t; e < 1024; e += 512) {
        int pos = e >> 4, j8 = (e & 15) * 8;
        float hv[8], wv[8], bv[8];
        ld_bf8(hrow + pos * 128 + j8, hv);
        int ni = (h * 64 + pos) * 128 + j8;
        ldp8(n0w, ni, md, wv);
        ldp8(n0b, ni, md, bv);
#pragma unroll
        for (int j = 0; j < 8; ++j)
            hdn[pos * 129 + j8 + j] = (hv[j] - mean) * rstd * wv[j] + bv[j];
    }
    __syncthreads();

    int cg  = __builtin_amdgcn_readfirstlane(t >> 6);   // 0..7
    int pos = t & 63;
    float acc[8];
#pragma unroll
    for (int ci = 0; ci < 8; ++ci) acc[ci] = 0.f;
    for (int j = 0; j < 128; ++j) {
        float hv = hdn[pos * 129 + j];
        const float* fw = fc1t + j * 64 + cg * 8;
#pragma unroll
        for (int ci = 0; ci < 8; ++ci) acc[ci] = fmaf(fw[ci], hv, acc[ci]);
    }
    int mmode = mflags[0];
    int midx = ((step * 8 + b) * 64 + h) * 64 + pos;
    int m;
    if (mmode == 0)      m = ((const int*)mraw)[midx] != 0;
    else if (mmode == 1) m = ((const unsigned char*)mraw)[midx] != 0;
    else if (mmode == 2) m = ((const unsigned short*)mraw)[midx] != 0;
    else                 m = ((const float*)mraw)[midx] != 0.0f;

    int idx = ((b * 64 + h) * 64 + pos) * 64 + cg * 8;
    float4 x0 = *(const float4*)&xio[idx];
    float4 x1 = *(const float4*)&xio[idx + 4];
    float xv[8] = {x0.x, x0.y, x0.z, x0.w, x1.x, x1.y, x1.z, x1.w};
    if (cg == 0) c0buf[(b * 64 + h) * 64 + pos] = xv[0];  // pre-update ch0
    float xn[8];
#pragma unroll
    for (int ci = 0; ci < 8; ++ci) {
        xn[ci] = finz(m ? (xv[ci] + acc[ci]) : xv[ci]);
        ys[pos * 65 + cg * 8 + ci] = xn[ci];
    }
    *(float4*)&xio[idx]     = make_float4(xn[0], xn[1], xn[2], xn[3]);
    *(float4*)&xio[idx + 4] = make_float4(xn[4], xn[5], xn[6], xn[7]);
    __syncthreads();

    // ln1 per token, in place on ys
    if (t < 64) {
        float s = 0.f, sq = 0.f;
        for (int c = 0; c < 64; ++c) { float v = ys[t * 65 + c]; s += v; sq += v * v; }
        float mu = s * (1.f / 64.f);
        float vr = sq * (1.f / 64.f) - mu * mu;
        float rs = rsqrtf(fmaxf(vr, 0.f) + 1e-5f);
        for (int c = 0; c < 64; ++c) {
            float v = ys[t * 65 + c];
            ys[t * 65 + c] = (v - mu) * rs * ldp(ln1w, c, md) + ldp(ln1b, c, md);
        }
    }
    __syncthreads();

    // qkv projection: 24 outputs per thread
    float a2[24];
#pragma unroll
    for (int oi = 0; oi < 24; ++oi) a2[oi] = 0.f;
    for (int c = 0; c < 64; ++c) {
        float yv = ys[pos * 65 + c];
        const float* qw = qkvt + c * 192 + cg * 24;
#pragma unroll
        for (int oi = 0; oi < 24; ++oi) a2[oi] = fmaf(qw[oi], yv, a2[oi]);
    }
    union { uint4 u[3]; unsigned short s[24]; } pq;
#pragma unroll
    for (int oi = 0; oi < 24; ++oi) pq.s[oi] = f2bfu(a2[oi]);
    uint4* qrow = (uint4*)(qkv + (((b * 64 + h) * 64) + pos) * 192 + cg * 24);
    qrow[0] = pq.u[0]; qrow[1] = pq.u[1]; qrow[2] = pq.u[2];
}

// C2+D fused: 3x3 zero-padded local attention + out-proj + residual (t),
// then ln2 + GELU MLP + residual + ch0 restore; in-place state, optional out.
__global__ __launch_bounds__(512) void k_attn_ff(
    const bf16* __restrict__ qkv, float* __restrict__ xio,
    const float* __restrict__ c0buf, const float* __restrict__ outt,
    const float* __restrict__ ff1t, const float* __restrict__ ff2t,
    const void* __restrict__ outb, const void* __restrict__ ln2w,
    const void* __restrict__ ln2b, const void* __restrict__ ff1b,
    const void* __restrict__ ff2b, const int* __restrict__ mflags,
    void* __restrict__ dout, int write_out)
{
    __shared__ float sm[12736];
    int md = mflags[1];
    int bh = blockIdx.x;
    int b = bh >> 6, h = bh & 63;
    int t = threadIdx.x;

    if (t < 192) {
        int c = t & 63, r = t >> 6;
        sm[c * 199 + r * 66]      = 0.f;
        sm[c * 199 + r * 66 + 65] = 0.f;
    }
    for (int e = t; e < 1536; e += 512) {
        int c8 = (e & 7) * 8, w = (e >> 3) & 63, r = e >> 9;
        int hr = h - 1 + r;
        float f[8];
        if (hr >= 0 && hr <= 63) {
            ld_bf8(qkv + ((b * 64 + hr) * 64 + w) * 192 + 64 + c8, f);
        } else {
#pragma unroll
            for (int j = 0; j < 8; ++j) f[j] = 0.f;
        }
#pragma unroll
        for (int j = 0; j < 8; ++j) sm[(c8 + j) * 199 + r * 66 + w + 1] = f[j];
    }
    __syncthreads();

    int head = __builtin_amdgcn_readfirstlane((t >> 6) & 3);
    int pos  = t & 63;
    float q[16];
    {
        const bf16* qr = qkv + (((b * 64 + h) * 64) + pos) * 192 + head * 16;
        ld_bf8(qr, q); ld_bf8(qr + 8, q + 8);
    }

    float a[9];
#pragma unroll
    for (int r = 0; r < 3; ++r)
#pragma unroll
        for (int cxi = 0; cxi < 3; ++cxi) {
            float dot = 0.f;
#pragma unroll
            for (int d = 0; d < 16; ++d)
                dot = fmaf(q[d], sm[(head * 16 + d) * 199 + r * 66 + pos + cxi], dot);
            a[r * 3 + cxi] = dot * 0.25f;
        }
    float mx = a[0];
#pragma unroll
    for (int k = 1; k < 9; ++k) mx = fmaxf(mx, a[k]);
    float ssum = 0.f;
#pragma unroll
    for (int k = 0; k < 9; ++k) { a[k] = __expf(a[k] - mx); ssum += a[k]; }
    float inv = 1.f / ssum;
#pragma unroll
    for (int k = 0; k < 9; ++k) a[k] *= inv;
    __syncthreads();

    for (int e = t; e < 1536; e += 512) {
        int c8 = (e & 7) * 8, w = (e >> 3) & 63, r = e >> 9;
        int hr = h - 1 + r;
        float f[8];
        if (hr >= 0 && hr <= 63) {
            ld_bf8(qkv + ((b * 64 + hr) * 64 + w) * 192 + 128 + c8, f);
        } else {
#pragma unroll
            for (int j = 0; j < 8; ++j) f[j] = 0.f;
        }
#pragma unroll
        for (int j = 0; j < 8; ++j) sm[(c8 + j) * 199 + r * 66 + w + 1] = f[j];
    }
    __syncthreads();

    float o[16];
#pragma unroll
    for (int d = 0; d < 16; ++d) {
        float ov = 0.f;
#pragma unroll
        for (int r = 0; r < 3; ++r)
#pragma unroll
            for (int cxi = 0; cxi < 3; ++cxi)
                ov = fmaf(a[r * 3 + cxi], sm[(head * 16 + d) * 199 + r * 66 + pos + cxi], ov);
        o[d] = ov;
    }
    __syncthreads();
    if (t < 256) {
#pragma unroll
        for (int d = 0; d < 16; ++d) sm[pos * 65 + head * 16 + d] = o[d];
    }
    __syncthreads();

    int g = __builtin_amdgcn_readfirstlane(t >> 6);
    float acc[8];
#pragma unroll
    for (int ci = 0; ci < 8; ++ci) acc[ci] = ldp(outb, g * 8 + ci, md);
    for (int k = 0; k < 64; ++k) {
        float ov = sm[pos * 65 + k];
        const float* ow = outt + k * 64 + g * 8;
#pragma unroll
        for (int ci = 0; ci < 8; ++ci) acc[ci] = fmaf(ow[ci], ov, acc[ci]);
    }
    int idx = ((b * 64 + h) * 64 + pos) * 64 + g * 8;
    {
        float4 x0 = *(const float4*)&xio[idx];
        float4 x1 = *(const float4*)&xio[idx + 4];
        const float* xp = (const float*)&x0;
        float* ts = &sm[4224 + pos * 65 + g * 8];
#pragma unroll
        for (int ci = 0; ci < 4; ++ci) ts[ci] = xp[ci] + acc[ci];
        xp = (const float*)&x1;
#pragma unroll
        for (int ci = 0; ci < 4; ++ci) ts[4 + ci] = xp[ci] + acc[4 + ci];
    }
    __syncthreads();

    if (t < 64) {
        float s = 0.f, sq = 0.f;
        for (int c = 0; c < 64; ++c) { float v = sm[4224 + t * 65 + c]; s += v; sq += v * v; }
        float mu = s * (1.f / 64.f);
        float vr = sq * (1.f / 64.f) - mu * mu;
        float rs = rsqrtf(fmaxf(vr, 0.f) + 1e-5f);
        for (int c = 0; c < 64; ++c) {
            float v = sm[4224 + t * 65 + c];
            sm[8448 + t * 65 + c] = (v - mu) * rs * ldp(ln2w, c, md) + ldp(ln2b, c, md);
        }
    }
    __syncthreads();

#pragma unroll
    for (int mi = 0; mi < 8; ++mi) acc[mi] = ldp(ff1b, g * 8 + mi, md);
    for (int c = 0; c < 64; ++c) {
        float yv = sm[8448 + pos * 65 + c];
        const float* fw = ff1t + c * 64 + g * 8;
#pragma unroll
        for (int mi = 0; mi < 8; ++mi) acc[mi] = fmaf(fw[mi], yv, acc[mi]);
    }
    __syncthreads();
#pragma unroll
    for (int mi = 0; mi < 8; ++mi) {
        float v = acc[mi];
        sm[pos * 65 + g * 8 + mi] = 0.5f * v * (1.f + erff(v * 0.70710678118654752f));
    }
    __syncthreads();

#pragma unroll
    for (int ci = 0; ci < 8; ++ci) acc[ci] = ldp(ff2b, g * 8 + ci, md);
    for (int m = 0; m < 64; ++m) {
        float hv = sm[pos * 65 + m];
        const float* fw = ff2t + m * 64 + g * 8;
#pragma unroll
        for (int ci = 0; ci < 8; ++ci) acc[ci] = fmaf(fw[ci], hv, acc[ci]);
    }
    float fv[8];
#pragma unroll
    for (int ci = 0; ci < 8; ++ci) {
        float v = sm[4224 + pos * 65 + g * 8 + ci] + acc[ci];
        if (g == 0 && ci == 0) v = c0buf[(b * 64 + h) * 64 + pos];
        fv[ci] = finz(v);
    }
    *(float4*)&xio[idx]     = make_float4(fv[0], fv[1], fv[2], fv[3]);
    *(float4*)&xio[idx + 4] = make_float4(fv[4], fv[5], fv[6], fv[7]);
    if (write_out) {
        if (md) {
            *(float4*)&((float*)dout)[idx]     = make_float4(fv[0], fv[1], fv[2], fv[3]);
            *(float4*)&((float*)dout)[idx + 4] = make_float4(fv[4], fv[5], fv[6], fv[7]);
        } else {
            *(uint4*)&((bf16*)dout)[idx] = pk_bf8(fv);
        }
    }
}

// ---------------- launch ----------------

extern "C" void kernel_launch(void* const* d_in, const int* in_sizes, int n_in,
                              void* d_out, int out_size, void* d_ws, size_t ws_size,
                              hipStream_t stream) {
    (void)in_sizes; (void)n_in; (void)out_size; (void)ws_size;
    const void* x     = d_in[0];
    const void* masks = d_in[1];
    const void* p0w   = d_in[2];
    const void* p0b   = d_in[3];
    const void* p1w   = d_in[4];
    const void* p1b   = d_in[5];
    const void* fc0w  = d_in[6];
    const void* fc0b  = d_in[7];
    const void* fc1w  = d_in[8];
    const void* n0w   = d_in[9];
    const void* n0b   = d_in[10];
    const void* ln1w  = d_in[11];
    const void* ln1b  = d_in[12];
    const void* qkvw  = d_in[13];
    const void* outw  = d_in[14];
    const void* outb  = d_in[15];
    const void* ln2w  = d_in[16];
    const void* ln2b  = d_in[17];
    const void* ff1w  = d_in[18];
    const void* ff1b  = d_in[19];
    const void* ff2w  = d_in[20];
    const void* ff2b  = d_in[21];

    // compact workspace layout, ~21.6 MB total.
    char* wsb = (char*)d_ws;
    float* xst    = (float*)(wsb + 0);           //  8,388,608 B  fp32 state (in-place)
    bf16*  hd     = (bf16*) (wsb + 8388608);     // 12,582,912 B region
    bf16*  qkvb   = (bf16*) (wsb + 8388608);     //   (alias of hd)
    float* c0buf  = (float*)(wsb + 20971520);    //    131,072 B
    short* bt1    = (short*)(wsb + 21102592);    //    147,456 B (bf16 conv weights [128][576])
    short* fc0s   = (short*)(wsb + 21397504);    //     49,152 B (bf16 fc0 weights [128][192])
    float* fc1t   = (float*)(wsb + 21495808);    //     32,768 B
    float* qkvt   = (float*)(wsb + 21528576);    //     49,152 B
    float* outt   = (float*)(wsb + 21577728);    //     16,384 B
    float* ff1t   = (float*)(wsb + 21594112);    //     16,384 B
    float* ff2t   = (float*)(wsb + 21610496);    //     16,384 B
    float* accv   = (float*)(wsb + 21626880);    //        384 B
    int*   mflags = (int*)  (wsb + 21627264);    //         16 B

    k_detect<<<1, 256, 0, stream>>>((const uint4*)masks, (const uint4*)x, mflags, accv);
    k_cast<<<1024, 256, 0, stream>>>(x, xst, mflags, 262144);
    k_pack_bt1<<<288, 256, 0, stream>>>(p0w, p1w, bt1, mflags);
    k_pack_fc0<<<96, 256, 0, stream>>>(fc0w, fc0s, mflags);
    k_transpose<<<32, 256, 0, stream>>>(fc1w, fc1t, mflags, 64, 128);
    k_transpose<<<48, 256, 0, stream>>>(qkvw, qkvt, mflags, 192, 64);
    k_transpose<<<16, 256, 0, stream>>>(outw, outt, mflags, 64, 64);
    k_transpose<<<16, 256, 0, stream>>>(ff1w, ff1t, mflags, 64, 64);
    k_transpose<<<16, 256, 0, stream>>>(ff2w, ff2t, mflags, 64, 64);

    for (int s = 0; s < NSTEP; ++s) {
        k_perceive<<<512, 512, 0, stream>>>(xst, bt1, fc0s, p0b, p1b, fc0b, mflags, hd, accv, s);
        k_update_qkv<<<512, 512, 0, stream>>>(xst, hd, fc1t, n0w, n0b, masks, mflags, accv,
                                              c0buf, qkvt, ln1w, ln1b, qkvb, s);
        k_attn_ff<<<512, 512, 0, stream>>>(qkvb, xst, c0buf, outt, ff1t, ff2t,
                                           outb, ln2w, ln2b, ff1b, ff2b, mflags,
                                           d_out, (s == NSTEP - 1) ? 1 : 0);
    }
}

// Round 8
// 701.203 us; speedup vs baseline: 2.7377x; 1.3591x over previous
//
#include <hip/hip_runtime.h>
#include <hip/hip_bf16.h>

typedef __hip_bfloat16 bf16;
typedef __attribute__((ext_vector_type(8))) short bf16x8;
typedef __attribute__((ext_vector_type(4))) float f32x4;

#define NSTEP 6

static __device__ __forceinline__ float b2f(bf16 v) { return __bfloat162float(v); }

// dtype-dispatched param load: md==0 -> bf16, md==1 -> float32
static __device__ __forceinline__ float ldp(const void* p, int i, int md) {
    return md ? ((const float*)p)[i] : b2f(((const bf16*)p)[i]);
}
static __device__ __forceinline__ float finz(float v) {
    return (v == v && v * 0.0f == 0.0f) ? v : 0.0f;  // non-finite -> 0
}
static __device__ __forceinline__ unsigned short f2bfu(float v) {
    bf16 h = __float2bfloat16(v);
    return *(unsigned short*)&h;
}

// 8 consecutive bf16 -> 8 floats (one 16B load)
static __device__ __forceinline__ void ld_bf8(const bf16* p, float* f) {
    union { uint4 u; unsigned short s[8]; } r;
    r.u = *(const uint4*)p;
#pragma unroll
    for (int j = 0; j < 8; ++j) f[j] = __uint_as_float(((unsigned)r.s[j]) << 16);
}
// dtype-dispatched 8-wide param load (i multiple of 8)
static __device__ __forceinline__ void ldp8(const void* p, int i, int md, float* f) {
    if (md) {
        const float* fp = (const float*)p + i;
        float4 a = *(const float4*)fp, b = *(const float4*)(fp + 4);
        f[0]=a.x; f[1]=a.y; f[2]=a.z; f[3]=a.w; f[4]=b.x; f[5]=b.y; f[6]=b.z; f[7]=b.w;
    } else {
        ld_bf8((const bf16*)p + i, f);
    }
}
// pack 8 floats -> uint4 of bf16 (RNE)
static __device__ __forceinline__ uint4 pk_bf8(const float* f) {
    union { uint4 u; unsigned short s[8]; } r;
#pragma unroll
    for (int j = 0; j < 8; ++j) r.s[j] = f2bfu(f[j]);
    return r.u;
}

// ---------------- detect / pack / cast kernels ----------------

// flags[0]: masks dtype mode (0 int32, 1 u8, 2 16-bit, 3 f32)
// flags[1]: float-array dtype (0 bf16, 1 f32); also zeroes accv (96 floats)
__global__ void k_detect(const uint4* __restrict__ m4,
                         const uint4* __restrict__ x4,
                         int* __restrict__ flags, float* __restrict__ accv) {
    __shared__ int s3f, sup, slo, sf32;
    int t = threadIdx.x;
    if (t == 0) { s3f = 0; sup = 0; slo = 0; sf32 = 0; }
    if (t < 96) accv[t] = 0.f;
    __syncthreads();
    int l3f = 0, lup = 0, llo = 0, lf = 0;
    for (int i = t; i < 3072; i += 256) {
        uint4 v = m4[i];
        const unsigned* d = (const unsigned*)&v;
#pragma unroll
        for (int j = 0; j < 4; ++j) {
            unsigned w = d[j];
            unsigned x3f = w ^ 0x3F3F3F3Fu;
            if ((x3f - 0x01010101u) & ~x3f & 0x80808080u) l3f = 1;
            if (w & 0xFFFFFF00u) lup = 1;
            if (w & 0x0000FFFFu) llo = 1;
        }
    }
    for (int i = t; i < 4096; i += 256) {
        uint4 v = x4[i];
        const unsigned* d = (const unsigned*)&v;
#pragma unroll
        for (int j = 0; j < 4; ++j) {
            unsigned bb = (d[j] >> 8) & 0x7Fu;
            if (bb > 0x48u) lf = 1;
        }
    }
    if (l3f) atomicOr(&s3f, 1);
    if (lup) atomicOr(&sup, 1);
    if (llo) atomicOr(&slo, 1);
    if (lf)  atomicOr(&sf32, 1);
    __syncthreads();
    if (t == 0) {
        int mode;
        if (!s3f && !sup) mode = 0;
        else if (!s3f)    mode = 1;
        else if (slo)     mode = 2;
        else              mode = 3;
        flags[0] = mode;
        flags[1] = sf32;
    }
}

__global__ void k_cast(const void* __restrict__ in, float* __restrict__ out,
                       const int* __restrict__ mflags, int n8) {
    int md = mflags[1];
    int i = blockIdx.x * 256 + threadIdx.x;
    if (i < n8) {
        float f[8];
        ldp8(in, i * 8, md, f);
#pragma unroll
        for (int j = 0; j < 8; ++j) f[j] = finz(f[j]);
        *(float4*)&out[i * 8]     = make_float4(f[0], f[1], f[2], f[3]);
        *(float4*)&out[i * 8 + 4] = make_float4(f[4], f[5], f[6], f[7]);
    }
}

// out[k*R + r] = in[r*K + k]  (f32 packs for the VALU kernels)
__global__ void k_transpose(const void* __restrict__ in, float* __restrict__ out,
                            const int* __restrict__ mflags, int R, int K) {
    int md = mflags[1];
    int i = blockIdx.x * 256 + threadIdx.x;
    if (i < R * K) {
        int k = i / R, r = i % R;
        out[i] = ldp(in, r * K + k, md);
    }
}

// straight elementwise cast to bf16 (row-major B packs for MFMA: B[n][k]=W[n][k])
__global__ void k_pack_bf16(const void* __restrict__ in, short* __restrict__ out,
                            const int* __restrict__ mflags, int n) {
    int md = mflags[1];
    int i = blockIdx.x * 256 + threadIdx.x;
    if (i < n) out[i] = (short)f2bfu(ldp(in, i, md));
}

// bt1[o][k] bf16, k = (ky*3+kx)*64 + i ; o<64 -> p0_w, else p1_w ([O][I][3][3])
__global__ void k_pack_bt1(const void* __restrict__ p0, const void* __restrict__ p1,
                           short* __restrict__ out, const int* __restrict__ mflags) {
    int md = mflags[1];
    int i = blockIdx.x * 256 + threadIdx.x;
    if (i < 128 * 576) {
        int o = i / 576, k = i % 576;
        int kk = k >> 6, ii = k & 63;
        float v = (o < 64) ? ldp(p0, o * 576 + ii * 9 + kk, md)
                           : ldp(p1, (o - 64) * 576 + ii * 9 + kk, md);
        out[i] = (short)f2bfu(v);
    }
}

// ---------------- step kernels ----------------
// grid 512 = B*H rows, 512 threads (8 waves) per block.

// A (MFMA): conv-as-implicit-GEMM [64x128x576] + fc0 GEMM [64x128x192]
__global__ __launch_bounds__(512) void k_perceive(
    const float* __restrict__ xin, const short* __restrict__ bt1,
    const short* __restrict__ fc0s, const void* __restrict__ p0b,
    const void* __restrict__ p1b, const void* __restrict__ fc0b,
    const int* __restrict__ mflags, bf16* __restrict__ hd,
    float* __restrict__ accv, int step)
{
    __shared__ __align__(16) short xpad_s[3 * 66 * 72];
    __shared__ __align__(16) short P_s[64 * 200];
    __shared__ float red[32];
    int md = mflags[1];
    int bh = blockIdx.x;
    int b = bh >> 6, h = bh & 63;
    int t = threadIdx.x;

    for (int e = t; e < 1536; e += 512) {
        int c8 = e & 7, w = (e >> 3) & 63, r = e >> 9;
        int hr = h - 1 + r; hr = hr < 0 ? -hr : (hr > 63 ? 126 - hr : hr);
        const float* src = xin + ((((b << 6) + hr) << 6) | w) * 64 + c8 * 8;
        float f[8];
        float4 v0 = *(const float4*)src, v1 = *(const float4*)(src + 4);
        f[0]=v0.x; f[1]=v0.y; f[2]=v0.z; f[3]=v0.w; f[4]=v1.x; f[5]=v1.y; f[6]=v1.z; f[7]=v1.w;
        uint4 pv = pk_bf8(f);
        *(uint4*)&xpad_s[((r * 66) + w + 1) * 72 + c8 * 8] = pv;
        if (r == 1) *(uint4*)&P_s[w * 200 + c8 * 8] = pv;
    }
    if (t < 48) {
        int c8 = t & 7, side = (t >> 3) & 1, r = t >> 4;
        int hr = h - 1 + r; hr = hr < 0 ? -hr : (hr > 63 ? 126 - hr : hr);
        int wsrc = side ? 62 : 1, wp = side ? 65 : 0;
        const float* src = xin + ((((b << 6) + hr) << 6) | wsrc) * 64 + c8 * 8;
        float f[8];
        float4 v0 = *(const float4*)src, v1 = *(const float4*)(src + 4);
        f[0]=v0.x; f[1]=v0.y; f[2]=v0.z; f[3]=v0.w; f[4]=v1.x; f[5]=v1.y; f[6]=v1.z; f[7]=v1.w;
        *(uint4*)&xpad_s[((r * 66) + wp) * 72 + c8 * 8] = pk_bf8(f);
    }
    __syncthreads();

    int og  = __builtin_amdgcn_readfirstlane(t >> 6);
    int l   = t & 63, nl = l & 15, q = l >> 4;
    int mt0 = (og & 1) * 2;
    int nt0 = (og >> 1) * 2;
    int o0  = nt0 * 16 + nl, o1 = o0 + 16;

    f32x4 acc[2][2];
#pragma unroll
    for (int i = 0; i < 2; ++i)
#pragma unroll
        for (int j = 0; j < 2; ++j) acc[i][j] = (f32x4){0.f, 0.f, 0.f, 0.f};

    for (int kt = 0; kt < 18; ++kt) {
        int kk = kt >> 1, c0 = (kt & 1) << 5;
        int r = kk / 3, cxi = kk - r * 3;
        bf16x8 b0 = *(const bf16x8*)(bt1 + o0 * 576 + kt * 32 + q * 8);
        bf16x8 b1 = *(const bf16x8*)(bt1 + o1 * 576 + kt * 32 + q * 8);
        bf16x8 a0 = *(const bf16x8*)&xpad_s[((r * 66) + mt0 * 16 + nl + cxi) * 72 + c0 + q * 8];
        bf16x8 a1 = *(const bf16x8*)&xpad_s[((r * 66) + mt0 * 16 + 16 + nl + cxi) * 72 + c0 + q * 8];
        acc[0][0] = __builtin_amdgcn_mfma_f32_16x16x32_bf16(a0, b0, acc[0][0], 0, 0, 0);
        acc[0][1] = __builtin_amdgcn_mfma_f32_16x16x32_bf16(a0, b1, acc[0][1], 0, 0, 0);
        acc[1][0] = __builtin_amdgcn_mfma_f32_16x16x32_bf16(a1, b0, acc[1][0], 0, 0, 0);
        acc[1][1] = __builtin_amdgcn_mfma_f32_16x16x32_bf16(a1, b1, acc[1][1], 0, 0, 0);
    }
    {
        float bias0 = (o0 < 64) ? ldp(p0b, o0, md) : ldp(p1b, o0 - 64, md);
        float bias1 = (o1 < 64) ? ldp(p0b, o1, md) : ldp(p1b, o1 - 64, md);
#pragma unroll
        for (int i = 0; i < 2; ++i)
#pragma unroll
            for (int j = 0; j < 2; ++j) {
                int oo = j ? o1 : o0;
                float bb = j ? bias1 : bias0;
#pragma unroll
                for (int r2 = 0; r2 < 4; ++r2) {
                    int m = (mt0 + i) * 16 + q * 4 + r2;
                    P_s[m * 200 + 64 + oo] = (short)f2bfu(acc[i][j][r2] + bb);
                }
            }
    }
    __syncthreads();

#pragma unroll
    for (int i = 0; i < 2; ++i)
#pragma unroll
        for (int j = 0; j < 2; ++j) acc[i][j] = (f32x4){0.f, 0.f, 0.f, 0.f};
    for (int kt = 0; kt < 6; ++kt) {
        bf16x8 b0 = *(const bf16x8*)(fc0s + o0 * 192 + kt * 32 + q * 8);
        bf16x8 b1 = *(const bf16x8*)(fc0s + o1 * 192 + kt * 32 + q * 8);
        bf16x8 a0 = *(const bf16x8*)&P_s[(mt0 * 16 + nl) * 200 + kt * 32 + q * 8];
        bf16x8 a1 = *(const bf16x8*)&P_s[(mt0 * 16 + 16 + nl) * 200 + kt * 32 + q * 8];
        acc[0][0] = __builtin_amdgcn_mfma_f32_16x16x32_bf16(a0, b0, acc[0][0], 0, 0, 0);
        acc[0][1] = __builtin_amdgcn_mfma_f32_16x16x32_bf16(a0, b1, acc[0][1], 0, 0, 0);
        acc[1][0] = __builtin_amdgcn_mfma_f32_16x16x32_bf16(a1, b0, acc[1][0], 0, 0, 0);
        acc[1][1] = __builtin_amdgcn_mfma_f32_16x16x32_bf16(a1, b1, acc[1][1], 0, 0, 0);
    }
    float lsum = 0.f, lsq = 0.f;
    {
        float fb0 = ldp(fc0b, o0, md), fb1 = ldp(fc0b, o1, md);
#pragma unroll
        for (int i = 0; i < 2; ++i)
#pragma unroll
            for (int j = 0; j < 2; ++j) {
                int oo = j ? o1 : o0;
                float bb = j ? fb1 : fb0;
#pragma unroll
                for (int r2 = 0; r2 < 4; ++r2) {
                    int m = (mt0 + i) * 16 + q * 4 + r2;
                    float v = fmaxf(acc[i][j][r2] + bb, 0.f);
                    unsigned short hu = f2bfu(v);
                    hd[((bh << 6) + m) * 128 + oo] = *(bf16*)&hu;
                    float vr = __uint_as_float(((unsigned)hu) << 16);
                    lsum += vr; lsq += vr * vr;
                }
            }
    }
#pragma unroll
    for (int off = 32; off > 0; off >>= 1) {
        lsum += __shfl_down(lsum, off, 64);
        lsq  += __shfl_down(lsq,  off, 64);
    }
    if (l == 0) { red[og] = lsum; red[16 + og] = lsq; }
    __syncthreads();
    if (t == 0) {
        float a = 0.f, s2 = 0.f;
#pragma unroll
        for (int w = 0; w < 8; ++w) { a += red[w]; s2 += red[16 + w]; }
        atomicAdd(&accv[step * 16 + b * 2],     a);
        atomicAdd(&accv[step * 16 + b * 2 + 1], s2);
    }
}

// B+C1 fused: global LN0 + fc1 + mask + residual (in-place on x) then
// per-token LN1 (parallel, 8 lanes/token) + qkv projection.
__global__ __launch_bounds__(512) void k_update_qkv(
    float* __restrict__ xio, const bf16* __restrict__ hd,
    const float* __restrict__ fc1t, const void* __restrict__ n0w,
    const void* __restrict__ n0b, const void* __restrict__ mraw,
    const int* __restrict__ mflags, const float* __restrict__ accv,
    float* __restrict__ c0buf, const float* __restrict__ qkvt,
    const void* __restrict__ ln1w, const void* __restrict__ ln1b,
    bf16* __restrict__ qkv, int step)
{
    __shared__ float hdn[64 * 129];
    __shared__ float ys[64 * 65];
    int md = mflags[1];
    int bh = blockIdx.x;
    int b = bh >> 6, h = bh & 63;
    int t = threadIdx.x;
    const float invN = 1.f / 524288.f;
    float mean = accv[step * 16 + b * 2] * invN;
    float var  = accv[step * 16 + b * 2 + 1] * invN - mean * mean;
    float rstd = rsqrtf(fmaxf(var, 0.f) + 1e-5f);

    const bf16* hrow = hd + ((b * 64 + h) * 64) * 128;
    for (int e = t; e < 1024; e += 512) {
        int pos = e >> 4, j8 = (e & 15) * 8;
        float hv[8], wv[8], bv[8];
        ld_bf8(hrow + pos * 128 + j8, hv);
        int ni = (h * 64 + pos) * 128 + j8;
        ldp8(n0w, ni, md, wv);
        ldp8(n0b, ni, md, bv);
#pragma unroll
        for (int j = 0; j < 8; ++j)
            hdn[pos * 129 + j8 + j] = (hv[j] - mean) * rstd * wv[j] + bv[j];
    }
    __syncthreads();

    int cg  = __builtin_amdgcn_readfirstlane(t >> 6);   // 0..7
    int pos = t & 63;
    float acc[8];
#pragma unroll
    for (int ci = 0; ci < 8; ++ci) acc[ci] = 0.f;
    for (int j = 0; j < 128; ++j) {
        float hv = hdn[pos * 129 + j];
        const float* fw = fc1t + j * 64 + cg * 8;
#pragma unroll
        for (int ci = 0; ci < 8; ++ci) acc[ci] = fmaf(fw[ci], hv, acc[ci]);
    }
    int mmode = mflags[0];
    int midx = ((step * 8 + b) * 64 + h) * 64 + pos;
    int m;
    if (mmode == 0)      m = ((const int*)mraw)[midx] != 0;
    else if (mmode == 1) m = ((const unsigned char*)mraw)[midx] != 0;
    else if (mmode == 2) m = ((const unsigned short*)mraw)[midx] != 0;
    else                 m = ((const float*)mraw)[midx] != 0.0f;

    int idx = ((b * 64 + h) * 64 + pos) * 64 + cg * 8;
    float4 x0 = *(const float4*)&xio[idx];
    float4 x1 = *(const float4*)&xio[idx + 4];
    float xv[8] = {x0.x, x0.y, x0.z, x0.w, x1.x, x1.y, x1.z, x1.w};
    if (cg == 0) c0buf[(b * 64 + h) * 64 + pos] = xv[0];
    float xn[8];
#pragma unroll
    for (int ci = 0; ci < 8; ++ci) {
        xn[ci] = finz(m ? (xv[ci] + acc[ci]) : xv[ci]);
        ys[pos * 65 + cg * 8 + ci] = xn[ci];
    }
    *(float4*)&xio[idx]     = make_float4(xn[0], xn[1], xn[2], xn[3]);
    *(float4*)&xio[idx + 4] = make_float4(xn[4], xn[5], xn[6], xn[7]);
    __syncthreads();

    // ln1 parallel: 8 lanes per token
    {
        int tok = t >> 3, j8 = (t & 7) * 8;
        float v[8];
        float ls = 0.f, lq = 0.f;
#pragma unroll
        for (int ci = 0; ci < 8; ++ci) {
            v[ci] = ys[tok * 65 + j8 + ci];
            ls += v[ci]; lq += v[ci] * v[ci];
        }
#pragma unroll
        for (int off = 1; off < 8; off <<= 1) {
            ls += __shfl_xor(ls, off, 64);
            lq += __shfl_xor(lq, off, 64);
        }
        float mu = ls * (1.f / 64.f);
        float vr = lq * (1.f / 64.f) - mu * mu;
        float rs = rsqrtf(fmaxf(vr, 0.f) + 1e-5f);
        float wv[8], bv[8];
        ldp8(ln1w, j8, md, wv);
        ldp8(ln1b, j8, md, bv);
#pragma unroll
        for (int ci = 0; ci < 8; ++ci)
            ys[tok * 65 + j8 + ci] = (v[ci] - mu) * rs * wv[ci] + bv[ci];
    }
    __syncthreads();

    // qkv projection: 24 outputs per thread
    float a2[24];
#pragma unroll
    for (int oi = 0; oi < 24; ++oi) a2[oi] = 0.f;
    for (int c = 0; c < 64; ++c) {
        float yv = ys[pos * 65 + c];
        const float* qw = qkvt + c * 192 + cg * 24;
#pragma unroll
        for (int oi = 0; oi < 24; ++oi) a2[oi] = fmaf(qw[oi], yv, a2[oi]);
    }
    union { uint4 u[3]; unsigned short s[24]; } pq;
#pragma unroll
    for (int oi = 0; oi < 24; ++oi) pq.s[oi] = f2bfu(a2[oi]);
    uint4* qrow = (uint4*)(qkv + (((b * 64 + h) * 64) + pos) * 192 + cg * 24);
    qrow[0] = pq.u[0]; qrow[1] = pq.u[1]; qrow[2] = pq.u[2];
}

// C2+D fused: attention (VALU) + out-proj/MLP1/MLP2 on MFMA + parallel ln2.
__global__ __launch_bounds__(512) void k_attn_ff(
    const bf16* __restrict__ qkv, float* __restrict__ xio,
    const float* __restrict__ c0buf, const short* __restrict__ outs,
    const short* __restrict__ ff1s, const short* __restrict__ ff2s,
    const void* __restrict__ outb, const void* __restrict__ ln2w,
    const void* __restrict__ ln2b, const void* __restrict__ ff1b,
    const void* __restrict__ ff2b, const int* __restrict__ mflags,
    void* __restrict__ dout, int write_out)
{
    // byte map: phase A/B: kv fp32 [64][199] (50944 B).
    // after PV: Ao bf16 [64][72] @0 (9216 B); ts fp32 [64][65] @9216 (16640 B);
    // ys bf16 [64][72] @25856; hs bf16 [64][72] @35072. total 44288 < 50944.
    __shared__ __align__(16) char smraw[50944];
    float* kv = (float*)smraw;
    short* Ao = (short*)smraw;
    float* ts = (float*)(smraw + 9216);
    short* ys = (short*)(smraw + 25856);
    short* hs = (short*)(smraw + 35072);

    int md = mflags[1];
    int bh = blockIdx.x;
    int b = bh >> 6, h = bh & 63;
    int t = threadIdx.x;

    // zero halos
    if (t < 192) {
        int c = t & 63, r = t >> 6;
        kv[c * 199 + r * 66]      = 0.f;
        kv[c * 199 + r * 66 + 65] = 0.f;
    }
    // K staging
    for (int e = t; e < 1536; e += 512) {
        int c8 = (e & 7) * 8, w = (e >> 3) & 63, r = e >> 9;
        int hr = h - 1 + r;
        float f[8];
        if (hr >= 0 && hr <= 63) {
            ld_bf8(qkv + ((b * 64 + hr) * 64 + w) * 192 + 64 + c8, f);
        } else {
#pragma unroll
            for (int j = 0; j < 8; ++j) f[j] = 0.f;
        }
#pragma unroll
        for (int j = 0; j < 8; ++j) kv[(c8 + j) * 199 + r * 66 + w + 1] = f[j];
    }
    __syncthreads();

    int head = __builtin_amdgcn_readfirstlane((t >> 6) & 3);
    int pos  = t & 63;
    float q[16];
    {
        const bf16* qr = qkv + (((b * 64 + h) * 64) + pos) * 192 + head * 16;
        ld_bf8(qr, q); ld_bf8(qr + 8, q + 8);
    }

    float a[9];
#pragma unroll
    for (int r = 0; r < 3; ++r)
#pragma unroll
        for (int cxi = 0; cxi < 3; ++cxi) {
            float dot = 0.f;
#pragma unroll
            for (int d = 0; d < 16; ++d)
                dot = fmaf(q[d], kv[(head * 16 + d) * 199 + r * 66 + pos + cxi], dot);
            a[r * 3 + cxi] = dot * 0.25f;
        }
    float mx = a[0];
#pragma unroll
    for (int k = 1; k < 9; ++k) mx = fmaxf(mx, a[k]);
    float ssum = 0.f;
#pragma unroll
    for (int k = 0; k < 9; ++k) { a[k] = __expf(a[k] - mx); ssum += a[k]; }
    float inv = 1.f / ssum;
#pragma unroll
    for (int k = 0; k < 9; ++k) a[k] *= inv;
    __syncthreads();

    // V staging
    for (int e = t; e < 1536; e += 512) {
        int c8 = (e & 7) * 8, w = (e >> 3) & 63, r = e >> 9;
        int hr = h - 1 + r;
        float f[8];
        if (hr >= 0 && hr <= 63) {
            ld_bf8(qkv + ((b * 64 + hr) * 64 + w) * 192 + 128 + c8, f);
        } else {
#pragma unroll
            for (int j = 0; j < 8; ++j) f[j] = 0.f;
        }
#pragma unroll
        for (int j = 0; j < 8; ++j) kv[(c8 + j) * 199 + r * 66 + w + 1] = f[j];
    }
    __syncthreads();

    float o[16];
#pragma unroll
    for (int d = 0; d < 16; ++d) {
        float ov = 0.f;
#pragma unroll
        for (int r = 0; r < 3; ++r)
#pragma unroll
            for (int cxi = 0; cxi < 3; ++cxi)
                ov = fmaf(a[r * 3 + cxi], kv[(head * 16 + d) * 199 + r * 66 + pos + cxi], ov);
        o[d] = ov;
    }
    __syncthreads();   // kv dead; regions reused below

    // Ao bf16 [pos][72] (first half-block only; second half is duplicate)
    if (t < 256) {
        *(uint4*)&Ao[pos * 72 + head * 16]     = pk_bf8(o);
        *(uint4*)&Ao[pos * 72 + head * 16 + 8] = pk_bf8(o + 8);
    }
    __syncthreads();

    // ---- MFMA phases: 64x64x64 GEMMs, wave og: mt = og&3, n-tiles {nt0,nt0+1}
    int og = __builtin_amdgcn_readfirstlane(t >> 6);
    int l = t & 63, nl = l & 15, qd = l >> 4;
    int mt = og & 3;
    int nt0 = (og >> 2) * 2;
    int o0 = nt0 * 16 + nl, o1 = o0 + 16;

    // out-proj
    {
        f32x4 pa[2];
        pa[0] = (f32x4){0.f,0.f,0.f,0.f}; pa[1] = (f32x4){0.f,0.f,0.f,0.f};
#pragma unroll
        for (int kt = 0; kt < 2; ++kt) {
            bf16x8 av = *(const bf16x8*)&Ao[(mt * 16 + nl) * 72 + kt * 32 + qd * 8];
            bf16x8 b0 = *(const bf16x8*)(outs + o0 * 64 + kt * 32 + qd * 8);
            bf16x8 b1 = *(const bf16x8*)(outs + o1 * 64 + kt * 32 + qd * 8);
            pa[0] = __builtin_amdgcn_mfma_f32_16x16x32_bf16(av, b0, pa[0], 0, 0, 0);
            pa[1] = __builtin_amdgcn_mfma_f32_16x16x32_bf16(av, b1, pa[1], 0, 0, 0);
        }
        float ob0 = ldp(outb, o0, md), ob1 = ldp(outb, o1, md);
#pragma unroll
        for (int j = 0; j < 2; ++j)
#pragma unroll
            for (int r2 = 0; r2 < 4; ++r2) {
                int m = mt * 16 + qd * 4 + r2;
                ts[m * 65 + (j ? o1 : o0)] = pa[j][r2] + (j ? ob1 : ob0);
            }
    }
    __syncthreads();

    // residual add (vectorized xio read)
    int idx = ((bh << 6) + pos) * 64 + (t >> 6) * 8;
    {
        int cg2 = t >> 6;
        float4 x0 = *(const float4*)&xio[idx];
        float4 x1 = *(const float4*)&xio[idx + 4];
        float* tp = &ts[pos * 65 + cg2 * 8];
        tp[0] += x0.x; tp[1] += x0.y; tp[2] += x0.z; tp[3] += x0.w;
        tp[4] += x1.x; tp[5] += x1.y; tp[6] += x1.z; tp[7] += x1.w;
    }
    __syncthreads();

    // ln2 parallel (8 lanes/token) -> ys bf16
    {
        int tok = t >> 3, j8 = (t & 7) * 8;
        float v[8];
        float ls = 0.f, lq = 0.f;
#pragma unroll
        for (int ci = 0; ci < 8; ++ci) {
            v[ci] = ts[tok * 65 + j8 + ci];
            ls += v[ci]; lq += v[ci] * v[ci];
        }
#pragma unroll
        for (int off = 1; off < 8; off <<= 1) {
            ls += __shfl_xor(ls, off, 64);
            lq += __shfl_xor(lq, off, 64);
        }
        float mu = ls * (1.f / 64.f);
        float vr = lq * (1.f / 64.f) - mu * mu;
        float rs = rsqrtf(fmaxf(vr, 0.f) + 1e-5f);
        float wv[8], bv[8];
        ldp8(ln2w, j8, md, wv);
        ldp8(ln2b, j8, md, bv);
        float yv[8];
#pragma unroll
        for (int ci = 0; ci < 8; ++ci) yv[ci] = (v[ci] - mu) * rs * wv[ci] + bv[ci];
        *(uint4*)&ys[tok * 72 + j8] = pk_bf8(yv);
    }
    __syncthreads();

    // MLP1 + exact GELU -> hs bf16
    {
        f32x4 ma[2];
        ma[0] = (f32x4){0.f,0.f,0.f,0.f}; ma[1] = (f32x4){0.f,0.f,0.f,0.f};
#pragma unroll
        for (int kt = 0; kt < 2; ++kt) {
            bf16x8 av = *(const bf16x8*)&ys[(mt * 16 + nl) * 72 + kt * 32 + qd * 8];
            bf16x8 b0 = *(const bf16x8*)(ff1s + o0 * 64 + kt * 32 + qd * 8);
            bf16x8 b1 = *(const bf16x8*)(ff1s + o1 * 64 + kt * 32 + qd * 8);
            ma[0] = __builtin_amdgcn_mfma_f32_16x16x32_bf16(av, b0, ma[0], 0, 0, 0);
            ma[1] = __builtin_amdgcn_mfma_f32_16x16x32_bf16(av, b1, ma[1], 0, 0, 0);
        }
        float f1b0 = ldp(ff1b, o0, md), f1b1 = ldp(ff1b, o1, md);
#pragma unroll
        for (int j = 0; j < 2; ++j)
#pragma unroll
            for (int r2 = 0; r2 < 4; ++r2) {
                int m = mt * 16 + qd * 4 + r2;
                float v = ma[j][r2] + (j ? f1b1 : f1b0);
                float g = 0.5f * v * (1.f + erff(v * 0.70710678118654752f));
                hs[m * 72 + (j ? o1 : o0)] = (short)f2bfu(g);
            }
    }
    __syncthreads();

    // MLP2 + residual into ts
    {
        f32x4 fa[2];
        fa[0] = (f32x4){0.f,0.f,0.f,0.f}; fa[1] = (f32x4){0.f,0.f,0.f,0.f};
#pragma unroll
        for (int kt = 0; kt < 2; ++kt) {
            bf16x8 av = *(const bf16x8*)&hs[(mt * 16 + nl) * 72 + kt * 32 + qd * 8];
            bf16x8 b0 = *(const bf16x8*)(ff2s + o0 * 64 + kt * 32 + qd * 8);
            bf16x8 b1 = *(const bf16x8*)(ff2s + o1 * 64 + kt * 32 + qd * 8);
            fa[0] = __builtin_amdgcn_mfma_f32_16x16x32_bf16(av, b0, fa[0], 0, 0, 0);
            fa[1] = __builtin_amdgcn_mfma_f32_16x16x32_bf16(av, b1, fa[1], 0, 0, 0);
        }
        float f2b0 = ldp(ff2b, o0, md), f2b1 = ldp(ff2b, o1, md);
#pragma unroll
        for (int j = 0; j < 2; ++j)
#pragma unroll
            for (int r2 = 0; r2 < 4; ++r2) {
                int m = mt * 16 + qd * 4 + r2;
                int oo = j ? o1 : o0;
                ts[m * 65 + oo] += fa[j][r2] + (j ? f2b1 : f2b0);
            }
    }
    __syncthreads();

    // final write: ch0 restore + state + optional out (vectorized)
    {
        int cg2 = t >> 6;
        float fv[8];
#pragma unroll
        for (int ci = 0; ci < 8; ++ci) {
            float v = ts[pos * 65 + cg2 * 8 + ci];
            if (cg2 == 0 && ci == 0) v = c0buf[(bh << 6) + pos];
            fv[ci] = finz(v);
        }
        *(float4*)&xio[idx]     = make_float4(fv[0], fv[1], fv[2], fv[3]);
        *(float4*)&xio[idx + 4] = make_float4(fv[4], fv[5], fv[6], fv[7]);
        if (write_out) {
            if (md) {
                *(float4*)&((float*)dout)[idx]     = make_float4(fv[0], fv[1], fv[2], fv[3]);
                *(float4*)&((float*)dout)[idx + 4] = make_float4(fv[4], fv[5], fv[6], fv[7]);
            } else {
                *(uint4*)&((bf16*)dout)[idx] = pk_bf8(fv);
            }
        }
    }
}

// ---------------- launch ----------------

extern "C" void kernel_launch(void* const* d_in, const int* in_sizes, int n_in,
                              void* d_out, int out_size, void* d_ws, size_t ws_size,
                              hipStream_t stream) {
    (void)in_sizes; (void)n_in; (void)out_size; (void)ws_size;
    const void* x     = d_in[0];
    const void* masks = d_in[1];
    const void* p0w   = d_in[2];
    const void* p0b   = d_in[3];
    const void* p1w   = d_in[4];
    const void* p1b   = d_in[5];
    const void* fc0w  = d_in[6];
    const void* fc0b  = d_in[7];
    const void* fc1w  = d_in[8];
    const void* n0w   = d_in[9];
    const void* n0b   = d_in[10];
    const void* ln1w  = d_in[11];
    const void* ln1b  = d_in[12];
    const void* qkvw  = d_in[13];
    const void* outw  = d_in[14];
    const void* outb  = d_in[15];
    const void* ln2w  = d_in[16];
    const void* ln2b  = d_in[17];
    const void* ff1w  = d_in[18];
    const void* ff1b  = d_in[19];
    const void* ff2w  = d_in[20];
    const void* ff2b  = d_in[21];

    // compact workspace layout, ~21.6 MB total.
    char* wsb = (char*)d_ws;
    float* xst    = (float*)(wsb + 0);           //  8,388,608 B fp32 state
    bf16*  hd     = (bf16*) (wsb + 8388608);     // 12,582,912 B region
    bf16*  qkvb   = (bf16*) (wsb + 8388608);     //   (alias of hd)
    float* c0buf  = (float*)(wsb + 20971520);    //    131,072 B
    short* bt1    = (short*)(wsb + 21102592);    //    147,456 B
    short* fc0s   = (short*)(wsb + 21397504);    //     49,152 B
    float* fc1t   = (float*)(wsb + 21446656);    //     32,768 B
    float* qkvt   = (float*)(wsb + 21479424);    //     49,152 B
    short* outs   = (short*)(wsb + 21528576);    //      8,192 B
    short* ff1s   = (short*)(wsb + 21536768);    //      8,192 B
    short* ff2s   = (short*)(wsb + 21544960);    //      8,192 B
    float* accv   = (float*)(wsb + 21553152);    //        384 B
    int*   mflags = (int*)  (wsb + 21553536);    //         16 B

    k_detect<<<1, 256, 0, stream>>>((const uint4*)masks, (const uint4*)x, mflags, accv);
    k_cast<<<1024, 256, 0, stream>>>(x, xst, mflags, 262144);
    k_pack_bt1<<<288, 256, 0, stream>>>(p0w, p1w, bt1, mflags);
    k_pack_bf16<<<96, 256, 0, stream>>>(fc0w, fc0s, mflags, 24576);
    k_transpose<<<32, 256, 0, stream>>>(fc1w, fc1t, mflags, 64, 128);
    k_transpose<<<48, 256, 0, stream>>>(qkvw, qkvt, mflags, 192, 64);
    k_pack_bf16<<<16, 256, 0, stream>>>(outw, outs, mflags, 4096);
    k_pack_bf16<<<16, 256, 0, stream>>>(ff1w, ff1s, mflags, 4096);
    k_pack_bf16<<<16, 256, 0, stream>>>(ff2w, ff2s, mflags, 4096);

    for (int s = 0; s < NSTEP; ++s) {
        k_perceive<<<512, 512, 0, stream>>>(xst, bt1, fc0s, p0b, p1b, fc0b, mflags, hd, accv, s);
        k_update_qkv<<<512, 512, 0, stream>>>(xst, hd, fc1t, n0w, n0b, masks, mflags, accv,
                                              c0buf, qkvt, ln1w, ln1b, qkvb, s);
        k_attn_ff<<<512, 512, 0, stream>>>(qkvb, xst, c0buf, outs, ff1s, ff2s,
                                           outb, ln2w, ln2b, ff1b, ff2b, mflags,
                                           d_out, (s == NSTEP - 1) ? 1 : 0);
    }
}